// Round 3
// baseline (8026.040 us; speedup 1.0000x reference)
//
#include <hip/hip_runtime.h>
#include <hip/hip_bf16.h>

typedef __hip_bfloat16 bf16;

__device__ __forceinline__ float ldv(const bf16* p){ return __bfloat162float(*p); }
__device__ __forceinline__ float ldv(const float* p){ return *p; }
__device__ __forceinline__ void stv(bf16* p, float v){ *p = __float2bfloat16(v); }
__device__ __forceinline__ void stv(float* p, float v){ *p = v; }

#define Bn   4
#define Cn   512
#define Hn   768
#define NHn  12
#define NEn  20
#define MMn  23
#define Pn   380
#define Mr   1520     // B*P
#define QSn  128
#define NEGV (-10000.0f)
#define SCL  0.036084391824351615f   // 1/sqrt(768)
#define BIGST 1000000

// ---------------- workspace layout (floats), lifetime-aliased ----------------
static const size_t o_EA = 0;         // ent_att [B][NE][NH][C]   dies after k_htatt
static const size_t o_EE = 491520;    // ent_emb [B*NE*MM][H]     dies after k_select
static const size_t o_EK = 1904640;   // ent_key [B*NE*MM][QS]    dies after k_select
static const size_t o_HA = 2140160;   // ht_att  [M][C]           dies after rs gemm
static const size_t o_HQ = 2918400;   // htq     [M][QS]          dies after k_select
static const size_t o_SH = 3112960;   // sel_h   [M][H]           dies after Whe gemm
static const size_t o_ST = 4280320;   // sel_t   [M][H]           dies after Wte gemm
static const size_t o_RS = 5447680;   // rs      [M][H]           dies after Wte gemm
static const size_t o_HS = 6615040;   // hs      [M][H]           lives to Wp1
static const size_t o_TS = 7782400;   // ts      [M][H]           lives to Wp1
// reuse region [0 .. 6,615,040):
static const size_t o_PB = 0;         // bilinear acc [M][H]
static const size_t o_FP = 1167360;   // feat_pp [M][1024]
static const size_t o_PT = 2723840;   // pairT   [M][H]
static const size_t o_Q  = 3891200;   // q       [M][H]
static const size_t o_KT = 5058560;   // kT      [B][H][P]
static const size_t o_V  = 0;         // v       [M][H]
static const size_t o_P2 = 1167360;   // pair2   [M][H]
static const size_t o_T1 = 2334720;   // t1      [M][H]
static const size_t o_DIAG = 8949760; // 2 ints: [0]=dtype flag (0=bf16,1=fp32), [1]=first NaN stage
// ws bytes needed: (8,949,762)*4 = 35,799,048

// ---------------- diagnostics ----------------

__global__ void k_init_diag(int* diag){ diag[0] = 0; diag[1] = BIGST; }

// scan raw half-words of seq: bf16 inputs from N(0,1) can never have exp==0xFF;
// an fp32 buffer misread as bf16 has ~0.4% such patterns.
__global__ __launch_bounds__(256) void k_scan(const unsigned short* __restrict__ s,
                                              int n, int* diag)
{
    int i = blockIdx.x*256 + threadIdx.x;
    if (i < n) {
        unsigned short u = s[i];
        if ((u & 0x7F80u) == 0x7F80u) atomicOr(&diag[0], 1);
    }
}

__global__ __launch_bounds__(256) void k_fillu(unsigned int* p, unsigned int v, int n){
    int i = blockIdx.x*256 + threadIdx.x;
    if (i < n) p[i] = v;
}

// ---------------- pipeline kernels (templated on input scalar T) ----------------

template<typename T>
__global__ __launch_bounds__(256) void k_ent_att(int want, int* diag,
    const void* __restrict__ attv, const int* __restrict__ midx,
    const void* __restrict__ mmv, float* __restrict__ ea)
{
    if (diag[0] != want) return;
    const T* att = (const T*)attv; const T* mmask = (const T*)mmv;
    int x = blockIdx.x;                 // (b*NE+e)*NH + nh
    int nh = x % NHn; int e = (x / NHn) % NEn; int b = x / (NHn * NEn);
    __shared__ int   sidx[MMn];
    __shared__ float smsk[MMn];
    int t = threadIdx.x;
    if (t < MMn) { sidx[t] = midx[(b*NEn+e)*MMn + t]; smsk[t] = ldv(&mmask[(b*NEn+e)*MMn + t]); }
    __syncthreads();
    float cnt = 0.f;
    for (int m = 0; m < MMn; m++) cnt += smsk[m];
    for (int c = t; c < Cn; c += 256) {
        float acc = 0.f;
        for (int m = 0; m < MMn; m++)
            acc += smsk[m] * ldv(&att[((size_t)(b*NHn+nh)*Cn + sidx[m])*Cn + c]);
        float r = acc / cnt;
        if (__builtin_isnan(r)) atomicMin(&diag[1], 1);
        ea[(size_t)x*Cn + c] = r;
    }
}

template<typename T>
__global__ __launch_bounds__(256) void k_ent_emb(int want, int* diag,
    const void* __restrict__ seqv, const int* __restrict__ midx,
    const void* __restrict__ mmv, float* __restrict__ ee)
{
    if (diag[0] != want) return;
    const T* seq = (const T*)seqv; const T* mmask = (const T*)mmv;
    int x = blockIdx.x;                 // (b*NE+e)*MM + m
    int b = x / (NEn*MMn);
    int idx = midx[x]; float msk = ldv(&mmask[x]);
    int t = threadIdx.x;
    for (int h = t; h < Hn; h += 256) {
        float r = msk * ldv(&seq[((size_t)b*Cn + idx)*Hn + h]);
        if (__builtin_isnan(r)) atomicMin(&diag[1], 2);
        ee[(size_t)x*Hn + h] = r;
    }
}

// dtype-independent (reads only fp32 ws + int hts): launched once
__global__ __launch_bounds__(256) void k_htatt(int* diag, const float* __restrict__ ea,
    const int* __restrict__ hts, float* __restrict__ hta)
{
    int row = blockIdx.x; int b = row / Pn;
    int he = hts[row*2], te = hts[row*2+1];
    __shared__ float sc[Cn];
    __shared__ float red[256];
    int t = threadIdx.x;
    const float* eah = ea + (size_t)(b*NEn+he)*NHn*Cn;
    const float* eat = ea + (size_t)(b*NEn+te)*NHn*Cn;
    for (int c = t; c < Cn; c += 256) {
        float a = 0.f;
        for (int nh = 0; nh < NHn; nh++) a += eah[nh*Cn+c]*eat[nh*Cn+c];
        sc[c] = a * (1.0f/NHn);
    }
    __syncthreads();
    float ps = sc[t] + sc[t+256];
    red[t] = ps; __syncthreads();
    for (int s = 128; s > 0; s >>= 1) { if (t < s) red[t] += red[t+s]; __syncthreads(); }
    float inv = 1.0f/(red[0] + 1e-5f);
    for (int c = t; c < Cn; c += 256) {
        float r = sc[c]*inv;
        if (__builtin_isnan(r)) atomicMin(&diag[1], 3);
        hta[(size_t)row*Cn + c] = r;
    }
}

// generic row-block GEMM with up-to-3-segment K concat (segments % 256 == 0):
// out[M,N] = act([inA|inB|inC][M,K](f32) @ W[K,N](T) + bias)
// FLAGS: 1=bias, 2=tanh, 4=store transposed per-batch [b][N][380], 8=store T, 16=final epilogue
template<int TILE, int NPT, int FLAGS, int STAGE, typename T>
__global__ __launch_bounds__(256) void k_gemm(int want, int* diag,
    const float* __restrict__ inA, const float* __restrict__ inB, const float* __restrict__ inC,
    int KA, int KB, int KC,
    const void* __restrict__ Wv, const void* __restrict__ biasv, void* __restrict__ outp,
    int N, int rowsPerBatch, long wStride)
{
    if (diag[0] != want) return;
    int badst = BIGST;
    if (FLAGS & 16) badst = diag[1];
    const T* W = (const T*)Wv; const T* bias = (const T*)biasv;
    __shared__ __align__(16) float lin[TILE][256];
    int t = threadIdx.x;
    int row0 = blockIdx.y*rowsPerBatch + blockIdx.x*TILE;
    const T* Wb = W + (size_t)blockIdx.y*wStride;
    int K = KA + KB + KC;
    float acc[TILE*NPT];
    #pragma unroll
    for (int x = 0; x < TILE*NPT; x++) acc[x] = 0.f;
    for (int kc = 0; kc < K; kc += 256) {
        const float* src; int ko; int Kl;
        if (kc < KA)            { src = inA; ko = kc;           Kl = KA; }
        else if (kc < KA + KB)  { src = inB; ko = kc - KA;      Kl = KB; }
        else                    { src = inC; ko = kc - KA - KB; Kl = KC; }
        __syncthreads();
        #pragma unroll
        for (int s = 0; s < TILE; s++) lin[s][t] = src[(size_t)(row0+s)*Kl + ko + t];
        __syncthreads();
        for (int kq = 0; kq < 64; kq++) {
            float w[4][NPT];
            #pragma unroll
            for (int j = 0; j < 4; j++)
                #pragma unroll
                for (int i = 0; i < NPT; i++) {
                    int n = t + i*256;
                    w[j][i] = (n < N) ? ldv(&Wb[(size_t)(kc+kq*4+j)*N + n]) : 0.f;
                }
            #pragma unroll
            for (int r = 0; r < TILE; r++) {
                float4 a = *(const float4*)&lin[r][kq*4];
                #pragma unroll
                for (int i = 0; i < NPT; i++)
                    acc[r*NPT+i] += a.x*w[0][i] + a.y*w[1][i] + a.z*w[2][i] + a.w*w[3][i];
            }
        }
    }
    #pragma unroll
    for (int i = 0; i < NPT; i++) {
        int n = t + i*256; if (n >= N) continue;
        float bv = (FLAGS & 1) ? ldv(&bias[n]) : 0.f;
        #pragma unroll
        for (int r = 0; r < TILE; r++) {
            float v = acc[r*NPT+i] + bv;
            if (FLAGS & 2) v = tanhf(v);
            if (__builtin_isnan(v)) { atomicMin(&diag[1], STAGE); v = 40000.f + 2000.f*STAGE; }
            if ((FLAGS & 16) && badst != BIGST) v = 40000.f + 2000.f*badst;
            int row = row0 + r;
            if (FLAGS & 4) {
                int bb = row / Pn; int pp = row % Pn;
                ((float*)outp)[((size_t)bb*N + n)*Pn + pp] = v;
            } else if (FLAGS & 8) {
                stv(((T*)outp) + (size_t)row*N + n, v);
            } else {
                ((float*)outp)[(size_t)row*N + n] = v;
            }
        }
    }
}

template<typename T>
__global__ __launch_bounds__(256) void k_select(int want, int* diag,
    const float* __restrict__ htq, const float* __restrict__ ekey, const float* __restrict__ ee,
    const void* __restrict__ mmv, const int* __restrict__ hts,
    float* __restrict__ selh, float* __restrict__ selt)
{
    if (diag[0] != want) return;
    const T* mmask = (const T*)mmv;
    int row = blockIdx.x; int side = blockIdx.y;
    int b = row / Pn;
    int e = hts[row*2 + side];
    __shared__ float qv[QSn];
    __shared__ float gsc[MMn];
    __shared__ float ew[MMn];
    int t = threadIdx.x;
    if (t < QSn) qv[t] = htq[(size_t)row*QSn + t];
    __syncthreads();
    if (t < MMn) {
        const float* kr = ekey + ((size_t)(b*NEn+e)*MMn + t)*QSn;
        float g = 0.f;
        for (int qq = 0; qq < QSn; qq++) g += qv[qq]*kr[qq];
        g *= SCL;
        float msk = ldv(&mmask[(b*NEn+e)*MMn + t]);
        gsc[t] = (msk > 0.f) ? g : NEGV;
    }
    __syncthreads();
    float mx = -1e30f;
    for (int m = 0; m < MMn; m++) mx = fmaxf(mx, gsc[m]);
    if (t < MMn) ew[t] = expf(gsc[t] - mx);
    __syncthreads();
    float s = 0.f;
    for (int m = 0; m < MMn; m++) s += ew[m];
    float invs = 1.0f/s;
    float* dst = side ? selt : selh;
    const float* eb = ee + (size_t)(b*NEn+e)*MMn*Hn;
    for (int h = t; h < Hn; h += 256) {
        float o = 0.f;
        for (int m = 0; m < MMn; m++) o += ew[m]*eb[(size_t)m*Hn + h];
        float r = o*invs;
        if (__builtin_isnan(r)) atomicMin(&diag[1], 7);
        dst[(size_t)row*Hn + h] = r;
    }
}

template<typename T>
__global__ __launch_bounds__(256) void k_blinit(int want, int* diag,
    const void* __restrict__ bblv, float* __restrict__ pb)
{
    if (diag[0] != want) return;
    const T* bbl = (const T*)bblv;
    int idx = blockIdx.x*256 + threadIdx.x;   // < Mr*Hn
    pb[idx] = ldv(&bbl[idx % Hn]);
}

template<typename T>
__global__ __launch_bounds__(256) void k_bilinear(int want, int* diag,
    const float* __restrict__ hs, const float* __restrict__ ts,
    const void* __restrict__ Wblv, float* __restrict__ pb)
{
    if (diag[0] != want) return;
    const T* Wbl = (const T*)Wblv;
    int t = threadIdx.x;
    int pbase = blockIdx.x * 32;
    int g  = blockIdx.z;          // 0..5, n = 2g, 2g+1
    __shared__ __align__(16) float hsl[32][65];
    __shared__ __align__(16) float tsl[32][65];
    __shared__ __align__(16) float scl[64][32];
    float acc[96];
    #pragma unroll
    for (int x = 0; x < 96; x++) acc[x] = 0.f;
    for (int nn = 0; nn < 2; nn++) {
        int n = g*2 + nn;
        __syncthreads();
        #pragma unroll
        for (int s = 0; s < 8; s++) {
            int e2 = t + s*256; int pp = e2 >> 6; int i = e2 & 63;
            int p = pbase + pp; if (p > Mr-1) p = Mr-1;
            hsl[pp][i] = hs[(size_t)p*Hn + n*64 + i];
            tsl[pp][i] = ts[(size_t)p*Hn + n*64 + i];
        }
        __syncthreads();
        for (int i = 0; i < 64; i++) {
            __syncthreads();
            #pragma unroll
            for (int s = 0; s < 8; s++) {
                int e2 = t + s*256; int j = e2 >> 5; int pp = e2 & 31;
                scl[j][pp] = hsl[pp][i]*tsl[pp][j];
            }
            __syncthreads();
            const T* wrow = Wbl + (size_t)((n*64+i)*64)*768;
            for (int j = 0; j < 64; j++) {
                float w0 = ldv(&wrow[(size_t)j*768 + t]);
                float w1 = ldv(&wrow[(size_t)j*768 + t + 256]);
                float w2 = ldv(&wrow[(size_t)j*768 + t + 512]);
                const float4* s4 = (const float4*)&scl[j][0];
                #pragma unroll
                for (int qd = 0; qd < 8; qd++) {
                    float4 sv = s4[qd];
                    acc[(qd*4+0)*3+0] += sv.x*w0; acc[(qd*4+0)*3+1] += sv.x*w1; acc[(qd*4+0)*3+2] += sv.x*w2;
                    acc[(qd*4+1)*3+0] += sv.y*w0; acc[(qd*4+1)*3+1] += sv.y*w1; acc[(qd*4+1)*3+2] += sv.y*w2;
                    acc[(qd*4+2)*3+0] += sv.z*w0; acc[(qd*4+2)*3+1] += sv.z*w1; acc[(qd*4+2)*3+2] += sv.z*w2;
                    acc[(qd*4+3)*3+0] += sv.w*w0; acc[(qd*4+3)*3+1] += sv.w*w1; acc[(qd*4+3)*3+2] += sv.w*w2;
                }
            }
        }
    }
    for (int pp = 0; pp < 32; pp++) {
        int p = pbase + pp; if (p >= Mr) break;
        float a0 = acc[pp*3+0], a1 = acc[pp*3+1], a2 = acc[pp*3+2];
        if (__builtin_isnan(a0) || __builtin_isnan(a1) || __builtin_isnan(a2))
            atomicMin(&diag[1], 11);
        float* dst = pb + (size_t)p*Hn;
        atomicAdd(&dst[t],       a0);
        atomicAdd(&dst[t + 256], a1);
        atomicAdd(&dst[t + 512], a2);
    }
}

template<typename T>
__global__ __launch_bounds__(256) void k_featpp(int want, int* diag,
    const float* __restrict__ pairbl, const void* __restrict__ posv,
    const int* __restrict__ hts, float* __restrict__ fpp)
{
    if (diag[0] != want) return;
    const T* pos = (const T*)posv;
    int row = blockIdx.x; int t = threadIdx.x;
    int he = hts[row*2], te = hts[row*2+1];
    float* dst = fpp + (size_t)row*1024;
    if (t < 128) { dst[t] = ldv(&pos[he*128 + t]); dst[896 + t] = ldv(&pos[te*128 + t]); }
    for (int h = t; h < Hn; h += 256) {
        float r = pairbl[(size_t)row*Hn + h];
        if (__builtin_isnan(r)) atomicMin(&diag[1], 12);
        dst[128 + h] = r;
    }
}

template<typename T>
__global__ __launch_bounds__(256) void k_graph(int want, int* diag,
    const float* __restrict__ q, const float* __restrict__ kT, const float* __restrict__ v,
    const void* __restrict__ visv, const float* __restrict__ pairT, float* __restrict__ pair2)
{
    if (diag[0] != want) return;
    const T* vis = (const T*)visv;
    int row = blockIdx.x; int b = row / Pn; int p = row % Pn;
    __shared__ float qs[Hn];
    __shared__ float sc[Pn];
    __shared__ float red[256];
    int t = threadIdx.x;
    for (int h = t; h < Hn; h += 256) qs[h] = q[(size_t)row*Hn + h];
    __syncthreads();
    for (int qq = t; qq < Pn; qq += 256) {
        const float* kcol = kT + (size_t)b*Hn*Pn + qq;
        float a = 0.f;
        for (int h = 0; h < Hn; h++) a += qs[h]*kcol[(size_t)h*Pn];
        a *= SCL;
        float ms = ldv(&vis[((size_t)b*Pn + p)*Pn + qq]);
        sc[qq] = (ms > 0.f) ? a : NEGV;
    }
    __syncthreads();
    float mx = -1e30f;
    for (int qq = t; qq < Pn; qq += 256) mx = fmaxf(mx, sc[qq]);
    red[t] = mx; __syncthreads();
    for (int s = 128; s > 0; s >>= 1) { if (t < s) red[t] = fmaxf(red[t], red[t+s]); __syncthreads(); }
    mx = red[0];
    __syncthreads();
    float ps = 0.f;
    for (int qq = t; qq < Pn; qq += 256) { float e2 = expf(sc[qq]-mx); sc[qq] = e2; ps += e2; }
    red[t] = ps; __syncthreads();
    for (int s = 128; s > 0; s >>= 1) { if (t < s) red[t] += red[t+s]; __syncthreads(); }
    float invs = 1.0f/red[0];
    __syncthreads();
    for (int d = t; d < Hn; d += 256) {
        float o = 0.f;
        for (int qq = 0; qq < Pn; qq++) o += sc[qq]*v[((size_t)b*Pn+qq)*Hn + d];
        float r = pairT[(size_t)row*Hn + d] + o*invs;
        if (__builtin_isnan(r)) atomicMin(&diag[1], 17);
        pair2[(size_t)row*Hn + d] = r;
    }
}

// ---------------- launch ----------------
extern "C" void kernel_launch(void* const* d_in, const int* in_sizes, int n_in,
                              void* d_out, int out_size, void* d_ws, size_t ws_size,
                              hipStream_t stream)
{
    // host-side sanity: input count/sizes and workspace size (deterministic per call)
    static const int want_sizes[26] = {
        1572864, 12582912, 1840, 1840, 3040, 577600,
        98304, 128, 98304, 128, 1179648, 768, 1179648, 768,
        37748736, 768, 786432, 768, 589824, 589824, 589824,
        1769472, 768, 74496, 97, 5376 };
    bool ok = (n_in == 26) && (out_size == Mr*97);
    if (ok) for (int i = 0; i < 26; i++) ok = ok && (in_sizes[i] == want_sizes[i]);
    if (!ok) {   // sentinel ~80000 in both bf16 and fp32 views (0x479C = bf16(79872))
        int n = out_size/2;
        k_fillu<<<(n+255)/256, 256, 0, stream>>>((unsigned int*)d_out, 0x479C479Cu, n);
        return;
    }
    if (ws_size < (size_t)(o_DIAG + 2) * 4) {  // sentinel ~60000 (0x476A)
        int n = out_size/2;
        k_fillu<<<(n+255)/256, 256, 0, stream>>>((unsigned int*)d_out, 0x476A476Au, n);
        return;
    }

    const void* seq  = d_in[0];
    const void* att  = d_in[1];
    const int*  midx = (const int*)d_in[2];
    const void* mmask= d_in[3];
    const int*  hts  = (const int*)d_in[4];
    const void* vis  = d_in[5];
    const void* Wcq = d_in[6];  const void* bcq = d_in[7];
    const void* Weq = d_in[8];  const void* beq = d_in[9];
    const void* Whe = d_in[10]; const void* bhe = d_in[11];
    const void* Wte = d_in[12]; const void* bte = d_in[13];
    const void* Wbl = d_in[14]; const void* bbl = d_in[15];
    const void* Wpp = d_in[16]; const void* bpp = d_in[17];
    const void* Wgq = d_in[18];
    const void* Wgk = d_in[19];
    const void* Wgv = d_in[20];
    const void* Wp1 = d_in[21]; const void* bp1 = d_in[22];
    const void* Wp2 = d_in[23]; const void* bp2 = d_in[24];
    const void* pos = d_in[25];
    float* ws = (float*)d_ws;
    int* diag = (int*)(ws + o_DIAG);
    const float* nul = nullptr;

    k_init_diag<<<1, 1, 0, stream>>>(diag);
    k_scan<<<1572864/256, 256, 0, stream>>>((const unsigned short*)seq, 1572864, diag);

    k_ent_att<bf16 ><<<Bn*NEn*NHn, 256, 0, stream>>>(0, diag, att, midx, mmask, ws + o_EA);
    k_ent_att<float><<<Bn*NEn*NHn, 256, 0, stream>>>(1, diag, att, midx, mmask, ws + o_EA);
    k_ent_emb<bf16 ><<<Bn*NEn*MMn, 256, 0, stream>>>(0, diag, seq, midx, mmask, ws + o_EE);
    k_ent_emb<float><<<Bn*NEn*MMn, 256, 0, stream>>>(1, diag, seq, midx, mmask, ws + o_EE);
    k_htatt<<<Mr, 256, 0, stream>>>(diag, ws + o_EA, hts, ws + o_HA);

    // rs = ht_att @ seq[b]  (stage 4)
    k_gemm<19,3,0,4,bf16 ><<<dim3(20,Bn), 256, 0, stream>>>(0, diag, ws + o_HA, nul, nul, Cn, 0, 0,
        seq, nullptr, (void*)(ws + o_RS), Hn, Pn, (long)Cn*Hn);
    k_gemm<19,3,0,4,float><<<dim3(20,Bn), 256, 0, stream>>>(1, diag, ws + o_HA, nul, nul, Cn, 0, 0,
        seq, nullptr, (void*)(ws + o_RS), Hn, Pn, (long)Cn*Hn);
    // htq (stage 5)
    k_gemm<16,1,1,5,bf16 ><<<dim3(95,1), 256, 0, stream>>>(0, diag, ws + o_RS, nul, nul, Hn, 0, 0,
        Wcq, bcq, (void*)(ws + o_HQ), QSn, Mr, 0);
    k_gemm<16,1,1,5,float><<<dim3(95,1), 256, 0, stream>>>(1, diag, ws + o_RS, nul, nul, Hn, 0, 0,
        Wcq, bcq, (void*)(ws + o_HQ), QSn, Mr, 0);
    // ent_key (stage 6)
    k_gemm<16,1,1,6,bf16 ><<<dim3(115,1), 256, 0, stream>>>(0, diag, ws + o_EE, nul, nul, Hn, 0, 0,
        Weq, beq, (void*)(ws + o_EK), QSn, Bn*NEn*MMn, 0);
    k_gemm<16,1,1,6,float><<<dim3(115,1), 256, 0, stream>>>(1, diag, ws + o_EE, nul, nul, Hn, 0, 0,
        Weq, beq, (void*)(ws + o_EK), QSn, Bn*NEn*MMn, 0);
    // select (stage 7)
    k_select<bf16 ><<<dim3(Mr,2), 256, 0, stream>>>(0, diag, ws + o_HQ, ws + o_EK, ws + o_EE,
        mmask, hts, ws + o_SH, ws + o_ST);
    k_select<float><<<dim3(Mr,2), 256, 0, stream>>>(1, diag, ws + o_HQ, ws + o_EK, ws + o_EE,
        mmask, hts, ws + o_SH, ws + o_ST);
    // hs/ts (stages 8,9)
    k_gemm<16,3,3,8,bf16 ><<<dim3(95,1), 256, 0, stream>>>(0, diag, ws + o_SH, ws + o_RS, nul, Hn, Hn, 0,
        Whe, bhe, (void*)(ws + o_HS), Hn, Mr, 0);
    k_gemm<16,3,3,8,float><<<dim3(95,1), 256, 0, stream>>>(1, diag, ws + o_SH, ws + o_RS, nul, Hn, Hn, 0,
        Whe, bhe, (void*)(ws + o_HS), Hn, Mr, 0);
    k_gemm<16,3,3,9,bf16 ><<<dim3(95,1), 256, 0, stream>>>(0, diag, ws + o_ST, ws + o_RS, nul, Hn, Hn, 0,
        Wte, bte, (void*)(ws + o_TS), Hn, Mr, 0);
    k_gemm<16,3,3,9,float><<<dim3(95,1), 256, 0, stream>>>(1, diag, ws + o_ST, ws + o_RS, nul, Hn, Hn, 0,
        Wte, bte, (void*)(ws + o_TS), Hn, Mr, 0);
    // bilinear (stages 10,11)
    k_blinit<bf16 ><<<(Mr*Hn)/256, 256, 0, stream>>>(0, diag, bbl, ws + o_PB);
    k_blinit<float><<<(Mr*Hn)/256, 256, 0, stream>>>(1, diag, bbl, ws + o_PB);
    k_bilinear<bf16 ><<<dim3(48,1,6), 256, 0, stream>>>(0, diag, ws + o_HS, ws + o_TS, Wbl, ws + o_PB);
    k_bilinear<float><<<dim3(48,1,6), 256, 0, stream>>>(1, diag, ws + o_HS, ws + o_TS, Wbl, ws + o_PB);
    // featpp (stage 12)
    k_featpp<bf16 ><<<Mr, 256, 0, stream>>>(0, diag, ws + o_PB, pos, hts, ws + o_FP);
    k_featpp<float><<<Mr, 256, 0, stream>>>(1, diag, ws + o_PB, pos, hts, ws + o_FP);
    // pairT (stage 13)
    k_gemm<16,3,3,13,bf16 ><<<dim3(95,1), 256, 0, stream>>>(0, diag, ws + o_FP, nul, nul, 1024, 0, 0,
        Wpp, bpp, (void*)(ws + o_PT), Hn, Mr, 0);
    k_gemm<16,3,3,13,float><<<dim3(95,1), 256, 0, stream>>>(1, diag, ws + o_FP, nul, nul, 1024, 0, 0,
        Wpp, bpp, (void*)(ws + o_PT), Hn, Mr, 0);
    // q/kT/v (stages 14,15,16)
    k_gemm<16,3,0,14,bf16 ><<<dim3(95,1), 256, 0, stream>>>(0, diag, ws + o_PT, nul, nul, Hn, 0, 0,
        Wgq, nullptr, (void*)(ws + o_Q), Hn, Mr, 0);
    k_gemm<16,3,0,14,float><<<dim3(95,1), 256, 0, stream>>>(1, diag, ws + o_PT, nul, nul, Hn, 0, 0,
        Wgq, nullptr, (void*)(ws + o_Q), Hn, Mr, 0);
    k_gemm<16,3,4,15,bf16 ><<<dim3(95,1), 256, 0, stream>>>(0, diag, ws + o_PT, nul, nul, Hn, 0, 0,
        Wgk, nullptr, (void*)(ws + o_KT), Hn, Mr, 0);
    k_gemm<16,3,4,15,float><<<dim3(95,1), 256, 0, stream>>>(1, diag, ws + o_PT, nul, nul, Hn, 0, 0,
        Wgk, nullptr, (void*)(ws + o_KT), Hn, Mr, 0);
    k_gemm<16,3,0,16,bf16 ><<<dim3(95,1), 256, 0, stream>>>(0, diag, ws + o_PT, nul, nul, Hn, 0, 0,
        Wgv, nullptr, (void*)(ws + o_V), Hn, Mr, 0);
    k_gemm<16,3,0,16,float><<<dim3(95,1), 256, 0, stream>>>(1, diag, ws + o_PT, nul, nul, Hn, 0, 0,
        Wgv, nullptr, (void*)(ws + o_V), Hn, Mr, 0);
    // graph (stage 17)
    k_graph<bf16 ><<<Mr, 256, 0, stream>>>(0, diag, ws + o_Q, ws + o_KT, ws + o_V, vis, ws + o_PT, ws + o_P2);
    k_graph<float><<<Mr, 256, 0, stream>>>(1, diag, ws + o_Q, ws + o_KT, ws + o_V, vis, ws + o_PT, ws + o_P2);
    // t1 (stage 18)
    k_gemm<16,3,3,18,bf16 ><<<dim3(95,1), 256, 0, stream>>>(0, diag, ws + o_HS, ws + o_TS, ws + o_P2,
        Hn, Hn, Hn, Wp1, bp1, (void*)(ws + o_T1), Hn, Mr, 0);
    k_gemm<16,3,3,18,float><<<dim3(95,1), 256, 0, stream>>>(1, diag, ws + o_HS, ws + o_TS, ws + o_P2,
        Hn, Hn, Hn, Wp1, bp1, (void*)(ws + o_T1), Hn, Mr, 0);
    // logits (stage 19, final epilogue: FLAGS = 1|8|16 = 25, store as T)
    k_gemm<16,1,25,19,bf16 ><<<dim3(95,1), 256, 0, stream>>>(0, diag, ws + o_T1, nul, nul, Hn, 0, 0,
        Wp2, bp2, d_out, 97, Mr, 0);
    k_gemm<16,1,25,19,float><<<dim3(95,1), 256, 0, stream>>>(1, diag, ws + o_T1, nul, nul, Hn, 0, 0,
        Wp2, bp2, d_out, 97, Mr, 0);
}

// Round 4
// 3066.828 us; speedup vs baseline: 2.6170x; 2.6170x over previous
//
#include <hip/hip_runtime.h>
#include <hip/hip_bf16.h>

#define Bn   4
#define Cn   512
#define Hn   768
#define NHn  12
#define NEn  20
#define MMn  23
#define Pn   380
#define Mr   1520     // B*P
#define QSn  128
#define NEGV (-10000.0f)
#define SCL  0.036084391824351615f   // 1/sqrt(768)

typedef unsigned int uint32;
typedef __attribute__((ext_vector_type(8))) short short8;
typedef __attribute__((ext_vector_type(4))) float float4v;

__device__ __forceinline__ unsigned short f2bs(float f){
    uint32 u = __builtin_bit_cast(uint32, f);
    uint32 r = (u + 0x7FFFu + ((u >> 16) & 1u)) >> 16;   // RNE
    return (unsigned short)r;
}
__device__ __forceinline__ float bs2f(unsigned short s){
    uint32 u = ((uint32)s) << 16;
    return __builtin_bit_cast(float, u);
}
__device__ __forceinline__ uint32 mulpack(uint32 tv, float hv){
    float lo = bs2f((unsigned short)(tv & 0xFFFFu)) * hv;
    float hi = bs2f((unsigned short)(tv >> 16)) * hv;
    return ((uint32)f2bs(lo)) | (((uint32)f2bs(hi)) << 16);
}

// ---------------- front-end kernels (all fp32 inputs) ----------------

__global__ __launch_bounds__(256) void k_ent_att(const float* __restrict__ att,
    const int* __restrict__ midx, const float* __restrict__ mmask, float* __restrict__ ea)
{
    int x = blockIdx.x;                 // (b*NE+e)*NH + nh
    int nh = x % NHn; int e = (x / NHn) % NEn; int b = x / (NHn * NEn);
    __shared__ int   sidx[MMn];
    __shared__ float smsk[MMn];
    int t = threadIdx.x;
    if (t < MMn) { sidx[t] = midx[(b*NEn+e)*MMn + t]; smsk[t] = mmask[(b*NEn+e)*MMn + t]; }
    __syncthreads();
    float cnt = 0.f;
    for (int m = 0; m < MMn; m++) cnt += smsk[m];
    for (int c = t; c < Cn; c += 256) {
        float acc = 0.f;
        for (int m = 0; m < MMn; m++)
            acc += smsk[m] * att[((size_t)(b*NHn+nh)*Cn + sidx[m])*Cn + c];
        ea[(size_t)x*Cn + c] = acc / cnt;
    }
}

__global__ __launch_bounds__(256) void k_ent_emb(const float* __restrict__ seq,
    const int* __restrict__ midx, const float* __restrict__ mmask, float* __restrict__ ee)
{
    int x = blockIdx.x;                 // (b*NE+e)*MM + m
    int b = x / (NEn*MMn);
    int idx = midx[x]; float msk = mmask[x];
    int t = threadIdx.x;
    for (int h = t; h < Hn; h += 256)
        ee[(size_t)x*Hn + h] = msk * seq[((size_t)b*Cn + idx)*Hn + h];
}

__global__ __launch_bounds__(256) void k_htatt(const float* __restrict__ ea,
    const int* __restrict__ hts, float* __restrict__ hta)
{
    int row = blockIdx.x; int b = row / Pn;
    int he = hts[row*2], te = hts[row*2+1];
    __shared__ float sc[Cn];
    __shared__ float red[256];
    int t = threadIdx.x;
    const float* eah = ea + (size_t)(b*NEn+he)*NHn*Cn;
    const float* eat = ea + (size_t)(b*NEn+te)*NHn*Cn;
    for (int c = t; c < Cn; c += 256) {
        float a = 0.f;
        for (int nh = 0; nh < NHn; nh++) a += eah[nh*Cn+c]*eat[nh*Cn+c];
        sc[c] = a * (1.0f/NHn);
    }
    __syncthreads();
    float ps = sc[t] + sc[t+256];
    red[t] = ps; __syncthreads();
    for (int s = 128; s > 0; s >>= 1) { if (t < s) red[t] += red[t+s]; __syncthreads(); }
    float inv = 1.0f/(red[0] + 1e-5f);
    for (int c = t; c < Cn; c += 256) hta[(size_t)row*Cn + c] = sc[c]*inv;
}

// generic row-block GEMM, z-tiled over N (256 cols per z):
// out[M,N] = act([inA|inB|inC][M,K](f32) @ W[K,N](f32) + bias); segments % 256 == 0
// FLAGS: 1=bias, 2=tanh, 4=store transposed per-batch [b][N][380]
template<int TILE, int FLAGS>
__global__ __launch_bounds__(256) void k_gemm(
    const float* __restrict__ inA, const float* __restrict__ inB, const float* __restrict__ inC,
    int KA, int KB, int KC,
    const float* __restrict__ W, const float* __restrict__ bias, float* __restrict__ outp,
    int N, int rowsPerBatch, long wStride)
{
    __shared__ __align__(16) float lin[TILE][256];
    int t = threadIdx.x;
    int n = blockIdx.z*256 + t;
    int row0 = blockIdx.y*rowsPerBatch + blockIdx.x*TILE;
    const float* Wb = W + (size_t)blockIdx.y*wStride;
    int K = KA + KB + KC;
    float acc[TILE];
    #pragma unroll
    for (int x = 0; x < TILE; x++) acc[x] = 0.f;
    for (int kc = 0; kc < K; kc += 256) {
        const float* src; int ko; int Kl;
        if (kc < KA)            { src = inA; ko = kc;           Kl = KA; }
        else if (kc < KA + KB)  { src = inB; ko = kc - KA;      Kl = KB; }
        else                    { src = inC; ko = kc - KA - KB; Kl = KC; }
        __syncthreads();
        #pragma unroll
        for (int s = 0; s < TILE; s++) lin[s][t] = src[(size_t)(row0+s)*Kl + ko + t];
        __syncthreads();
        for (int kq = 0; kq < 64; kq++) {
            float w[4];
            #pragma unroll
            for (int j = 0; j < 4; j++)
                w[j] = (n < N) ? Wb[(size_t)(kc+kq*4+j)*N + n] : 0.f;
            #pragma unroll
            for (int r = 0; r < TILE; r++) {
                float4 a = *(const float4*)&lin[r][kq*4];
                acc[r] += a.x*w[0] + a.y*w[1] + a.z*w[2] + a.w*w[3];
            }
        }
    }
    if (n < N) {
        float bv = (FLAGS & 1) ? bias[n] : 0.f;
        #pragma unroll
        for (int r = 0; r < TILE; r++) {
            float v = acc[r] + bv;
            if (FLAGS & 2) v = tanhf(v);
            int row = row0 + r;
            if (FLAGS & 4) {
                int bb = row / Pn; int pp = row % Pn;
                outp[((size_t)bb*N + n)*Pn + pp] = v;
            } else {
                outp[(size_t)row*N + n] = v;
            }
        }
    }
}

__global__ __launch_bounds__(256) void k_select(const float* __restrict__ htq,
    const float* __restrict__ ekey, const float* __restrict__ ee,
    const float* __restrict__ mmask, const int* __restrict__ hts,
    float* __restrict__ selh, float* __restrict__ selt)
{
    int row = blockIdx.x; int side = blockIdx.y;
    int b = row / Pn;
    int e = hts[row*2 + side];
    __shared__ float qv[QSn];
    __shared__ float gsc[MMn];
    __shared__ float ew[MMn];
    int t = threadIdx.x;
    if (t < QSn) qv[t] = htq[(size_t)row*QSn + t];
    __syncthreads();
    if (t < MMn) {
        const float* kr = ekey + ((size_t)(b*NEn+e)*MMn + t)*QSn;
        float g = 0.f;
        for (int qq = 0; qq < QSn; qq++) g += qv[qq]*kr[qq];
        g *= SCL;
        float msk = mmask[(b*NEn+e)*MMn + t];
        gsc[t] = (msk > 0.f) ? g : NEGV;
    }
    __syncthreads();
    float mx = -1e30f;
    for (int m = 0; m < MMn; m++) mx = fmaxf(mx, gsc[m]);
    if (t < MMn) ew[t] = expf(gsc[t] - mx);
    __syncthreads();
    float s = 0.f;
    for (int m = 0; m < MMn; m++) s += ew[m];
    float invs = 1.0f/s;
    float* dst = side ? selt : selh;
    const float* eb = ee + (size_t)(b*NEn+e)*MMn*Hn;
    for (int h = t; h < Hn; h += 256) {
        float o = 0.f;
        for (int m = 0; m < MMn; m++) o += ew[m]*eb[(size_t)m*Hn + h];
        dst[(size_t)row*Hn + h] = o*invs;
    }
}

__global__ __launch_bounds__(256) void k_blinit(const float* __restrict__ bbl, float* __restrict__ pb)
{
    int idx = blockIdx.x*256 + threadIdx.x;
    pb[idx] = bbl[idx % Hn];
}

// ---------------- fast path: Wbl transpose+bf16 and MFMA bilinear ----------------

// Wbl [49152][768] f32  ->  Wt [768][49152] bf16
__global__ __launch_bounds__(256) void k_wcvt(const float* __restrict__ Wbl,
                                              unsigned short* __restrict__ Wt)
{
    __shared__ unsigned short tl[64][72];
    int t = threadIdx.x;
    int k0 = blockIdx.x * 64, d0 = blockIdx.y * 64;
    int dl = t & 63, rq = t >> 6;
    for (int r = 0; r < 16; r++) {
        int kl = r*4 + rq;
        tl[dl][kl] = f2bs(Wbl[(size_t)(k0+kl)*Hn + d0 + dl]);
    }
    __syncthreads();
    int dd = t >> 2, kk0 = (t & 3) * 16;
    uint4 a = *(const uint4*)&tl[dd][kk0];
    uint4 b = *(const uint4*)&tl[dd][kk0+8];
    uint4* dst = (uint4*)&Wt[(size_t)(d0+dd)*49152 + k0 + kk0];
    dst[0] = a; dst[1] = b;
}

// pair[p][d] += sum over n in {2g,2g+1} of  (hs[p,64n+i]*ts[p,64n+j]) * Wbl[(64n+i)*64+j][d]
// MFMA: A = Wt rows (m=d), B = built pair tile (n=p), D[m=d][n=p]
__global__ __launch_bounds__(256,2) void k_blmfma(const float* __restrict__ hs,
    const float* __restrict__ ts, const unsigned short* __restrict__ Wt,
    float* __restrict__ pb)
{
    __shared__ unsigned short hsl[2][64][72];
    __shared__ unsigned short tsl[2][64][72];
    __shared__ unsigned short ap[64][136];   // [p][k-local 0..127], row 272B (16B-aligned)
    int t = threadIdx.x;
    int p0 = blockIdx.x * 64;
    int d0 = blockIdx.y * 256;
    int g  = blockIdx.z;                     // n = 2g, 2g+1
    int lane = t & 63;
    int w = t >> 6;                          // wave -> 64-wide d quarter
    int ln = lane & 15, q = lane >> 4;

    {   // stage hs/ts (fp32 -> bf16) for both n of this group
        int p = t & 63; int c0 = (t >> 6) * 16;
        int pr = p0 + p; if (pr > Mr-1) pr = Mr-1;
        for (int nn = 0; nn < 2; nn++) {
            int n = 2*g + nn;
            const float* hp = hs + (size_t)pr*Hn + n*64 + c0;
            const float* tp = ts + (size_t)pr*Hn + n*64 + c0;
            #pragma unroll
            for (int c = 0; c < 16; c++) {
                hsl[nn][p][c0+c] = f2bs(hp[c]);
                tsl[nn][p][c0+c] = f2bs(tp[c]);
            }
        }
    }
    float4v acc[4][4];
    #pragma unroll
    for (int e = 0; e < 4; e++)
        #pragma unroll
        for (int f = 0; f < 4; f++) acc[e][f] = (float4v)0.f;
    const unsigned short* WtW = Wt + (size_t)(d0 + w*64)*49152;

    for (int nn = 0; nn < 2; nn++) {
        int n = 2*g + nn;
        for (int i0 = 0; i0 < 64; i0 += 2) {
            __syncthreads();
            {   // build ap[p][ii*64+j] = hs[p][i0+ii] * ts[p][j]   (2 i's, 64 j's)
                int p = t & 63, seg = t >> 6;
                int ii = seg >> 1, j0 = (seg & 1) * 32;
                float hv = bs2f(hsl[nn][p][i0+ii]);
                const uint4* tsrc = (const uint4*)&tsl[nn][p][j0];
                uint4* dstp = (uint4*)&ap[p][ii*64 + j0];
                #pragma unroll
                for (int u = 0; u < 4; u++) {
                    uint4 tv = tsrc[u];
                    uint4 o;
                    o.x = mulpack(tv.x, hv); o.y = mulpack(tv.y, hv);
                    o.z = mulpack(tv.z, hv); o.w = mulpack(tv.w, hv);
                    dstp[u] = o;
                }
            }
            __syncthreads();
            size_t kbase = (size_t)n*4096 + (size_t)i0*64;
            #pragma unroll
            for (int c = 0; c < 4; c++) {
                short8 a[4], b[4];
                #pragma unroll
                for (int f = 0; f < 4; f++)
                    a[f] = *(const short8*)&WtW[(size_t)(f*16 + ln)*49152 + kbase + c*32 + q*8];
                #pragma unroll
                for (int e = 0; e < 4; e++)
                    b[e] = *(const short8*)&ap[e*16 + ln][c*32 + q*8];
                #pragma unroll
                for (int e = 0; e < 4; e++)
                    #pragma unroll
                    for (int f = 0; f < 4; f++)
                        acc[e][f] = __builtin_amdgcn_mfma_f32_16x16x32_bf16(a[f], b[e], acc[e][f], 0, 0, 0);
            }
        }
    }
    // D: col(n)=lane&15 -> p, row(m)=(lane>>4)*4+r -> d
    for (int e = 0; e < 4; e++) {
        int p = p0 + e*16 + ln;
        if (p >= Mr) continue;
        for (int f = 0; f < 4; f++) {
            int dbase = d0 + w*64 + f*16 + q*4;
            #pragma unroll
            for (int r = 0; r < 4; r++)
                atomicAdd(&pb[(size_t)p*Hn + dbase + r], acc[e][f][r]);
        }
    }
}

// ---------------- fallback bilinear (fp32 VALU, 12-way K split) ----------------
__global__ __launch_bounds__(256) void k_bilinear_fb(const float* __restrict__ hs,
    const float* __restrict__ ts, const float* __restrict__ Wbl, float* __restrict__ pb)
{
    int t = threadIdx.x;
    int pbase = blockIdx.x * 32;
    int n = blockIdx.z;               // 0..11
    __shared__ __align__(16) float hsl[32][65];
    __shared__ __align__(16) float tsl[32][65];
    __shared__ __align__(16) float scl[64][32];
    float acc[96];
    #pragma unroll
    for (int x = 0; x < 96; x++) acc[x] = 0.f;
    #pragma unroll
    for (int s = 0; s < 8; s++) {
        int e2 = t + s*256; int pp = e2 >> 6; int i = e2 & 63;
        int p = pbase + pp; if (p > Mr-1) p = Mr-1;
        hsl[pp][i] = hs[(size_t)p*Hn + n*64 + i];
        tsl[pp][i] = ts[(size_t)p*Hn + n*64 + i];
    }
    __syncthreads();
    for (int i = 0; i < 64; i++) {
        __syncthreads();
        #pragma unroll
        for (int s = 0; s < 8; s++) {
            int e2 = t + s*256; int j = e2 >> 5; int pp = e2 & 31;
            scl[j][pp] = hsl[pp][i]*tsl[pp][j];
        }
        __syncthreads();
        const float* wrow = Wbl + (size_t)((n*64+i)*64)*Hn;
        for (int j = 0; j < 64; j++) {
            float w0 = wrow[(size_t)j*Hn + t];
            float w1 = wrow[(size_t)j*Hn + t + 256];
            float w2 = wrow[(size_t)j*Hn + t + 512];
            const float4* s4 = (const float4*)&scl[j][0];
            #pragma unroll
            for (int qd = 0; qd < 8; qd++) {
                float4 sv = s4[qd];
                acc[(qd*4+0)*3+0] += sv.x*w0; acc[(qd*4+0)*3+1] += sv.x*w1; acc[(qd*4+0)*3+2] += sv.x*w2;
                acc[(qd*4+1)*3+0] += sv.y*w0; acc[(qd*4+1)*3+1] += sv.y*w1; acc[(qd*4+1)*3+2] += sv.y*w2;
                acc[(qd*4+2)*3+0] += sv.z*w0; acc[(qd*4+2)*3+1] += sv.z*w1; acc[(qd*4+2)*3+2] += sv.z*w2;
                acc[(qd*4+3)*3+0] += sv.w*w0; acc[(qd*4+3)*3+1] += sv.w*w1; acc[(qd*4+3)*3+2] += sv.w*w2;
            }
        }
    }
    for (int pp = 0; pp < 32; pp++) {
        int p = pbase + pp; if (p >= Mr) break;
        float* dst = pb + (size_t)p*Hn;
        atomicAdd(&dst[t],       acc[pp*3+0]);
        atomicAdd(&dst[t + 256], acc[pp*3+1]);
        atomicAdd(&dst[t + 512], acc[pp*3+2]);
    }
}

// ---------------- back-end ----------------

__global__ __launch_bounds__(256) void k_featpp(const float* __restrict__ pairbl,
    const float* __restrict__ pos, const int* __restrict__ hts, float* __restrict__ fpp)
{
    int row = blockIdx.x; int t = threadIdx.x;
    int he = hts[row*2], te = hts[row*2+1];
    float* dst = fpp + (size_t)row*1024;
    if (t < 128) { dst[t] = pos[he*128 + t]; dst[896 + t] = pos[te*128 + t]; }
    for (int h = t; h < Hn; h += 256) dst[128 + h] = pairbl[(size_t)row*Hn + h];
}

__global__ __launch_bounds__(256) void k_graph(const float* __restrict__ q,
    const float* __restrict__ kT, const float* __restrict__ v, const float* __restrict__ vis,
    const float* __restrict__ pairT, float* __restrict__ pair2)
{
    int row = blockIdx.x; int b = row / Pn; int p = row % Pn;
    __shared__ float qs[Hn];
    __shared__ float sc[Pn];
    __shared__ float red[256];
    int t = threadIdx.x;
    for (int h = t; h < Hn; h += 256) qs[h] = q[(size_t)row*Hn + h];
    __syncthreads();
    for (int qq = t; qq < Pn; qq += 256) {
        const float* kcol = kT + (size_t)b*Hn*Pn + qq;
        float a = 0.f;
        for (int h = 0; h < Hn; h++) a += qs[h]*kcol[(size_t)h*Pn];
        a *= SCL;
        float ms = vis[((size_t)b*Pn + p)*Pn + qq];
        sc[qq] = (ms > 0.f) ? a : NEGV;
    }
    __syncthreads();
    float mx = -1e30f;
    for (int qq = t; qq < Pn; qq += 256) mx = fmaxf(mx, sc[qq]);
    red[t] = mx; __syncthreads();
    for (int s = 128; s > 0; s >>= 1) { if (t < s) red[t] = fmaxf(red[t], red[t+s]); __syncthreads(); }
    mx = red[0];
    __syncthreads();
    float ps = 0.f;
    for (int qq = t; qq < Pn; qq += 256) { float e2 = expf(sc[qq]-mx); sc[qq] = e2; ps += e2; }
    red[t] = ps; __syncthreads();
    for (int s = 128; s > 0; s >>= 1) { if (t < s) red[t] += red[t+s]; __syncthreads(); }
    float invs = 1.0f/red[0];
    __syncthreads();
    for (int d = t; d < Hn; d += 256) {
        float o = 0.f;
        for (int qq = 0; qq < Pn; qq++) o += sc[qq]*v[((size_t)b*Pn+qq)*Hn + d];
        pair2[(size_t)row*Hn + d] = pairT[(size_t)row*Hn + d] + o*invs;
    }
}

// ---------------- launch ----------------
extern "C" void kernel_launch(void* const* d_in, const int* in_sizes, int n_in,
                              void* d_out, int out_size, void* d_ws, size_t ws_size,
                              hipStream_t stream)
{
    const float* seq  = (const float*)d_in[0];
    const float* att  = (const float*)d_in[1];
    const int*   midx = (const int*)d_in[2];
    const float* mmask= (const float*)d_in[3];
    const int*   hts  = (const int*)d_in[4];
    const float* vis  = (const float*)d_in[5];
    const float* Wcq = (const float*)d_in[6];  const float* bcq = (const float*)d_in[7];
    const float* Weq = (const float*)d_in[8];  const float* beq = (const float*)d_in[9];
    const float* Whe = (const float*)d_in[10]; const float* bhe = (const float*)d_in[11];
    const float* Wte = (const float*)d_in[12]; const float* bte = (const float*)d_in[13];
    const float* Wbl = (const float*)d_in[14]; const float* bbl = (const float*)d_in[15];
    const float* Wpp = (const float*)d_in[16]; const float* bpp = (const float*)d_in[17];
    const float* Wgq = (const float*)d_in[18];
    const float* Wgk = (const float*)d_in[19];
    const float* Wgv = (const float*)d_in[20];
    const float* Wp1 = (const float*)d_in[21]; const float* bp1 = (const float*)d_in[22];
    const float* Wp2 = (const float*)d_in[23]; const float* bp2 = (const float*)d_in[24];
    const float* pos = (const float*)d_in[25];
    float* ws = (float*)d_ws;
    float* out = (float*)d_out;
    const float* nul = nullptr;

    // ws layouts (floats). Fast path needs 22,376,448 f = 89.5 MB.
    bool fast = (ws_size >= 89505792ULL);
    size_t oHS, oTS, oPB, X;
    if (fast) { oHS = 0; oTS = 1167360; oPB = 2334720; X = 3502080; }
    else      { oHS = 6615040; oTS = 7782400; oPB = 0; X = 0; }
    // early scratch (dead before bilinear) and late scratch (alive after) share X
    size_t oEA, oEE, oEK, oHA, oHQ, oSH, oST, oRS, oFP, oPT, oQ, oKT, oV, oP2, oT1;
    if (fast) {
        oEA = X;           oEE = X+491520;  oEK = X+1904640; oHA = X+2140160;
        oHQ = X+2918400;   oSH = X+3112960; oST = X+4280320; oRS = X+5447680;
        oFP = X;           oPT = X+1556480; oQ  = X+2723840; oKT = X+3891200;
        oV  = X+5058560;   oP2 = X+6225920; oT1 = X+7393280;
    } else {
        oEA = 0;       oEE = 491520;  oEK = 1904640; oHA = 2140160;
        oHQ = 2918400; oSH = 3112960; oST = 4280320; oRS = 5447680;
        oFP = 1167360; oPT = 2723840; oQ  = 3891200; oKT = 5058560;
        oV  = 0;       oP2 = 1167360; oT1 = 2334720;
    }
    unsigned short* Wt = (unsigned short*)(ws + X);   // fast path only, aliases early scratch

    k_ent_att<<<Bn*NEn*NHn, 256, 0, stream>>>(att, midx, mmask, ws + oEA);
    k_ent_emb<<<Bn*NEn*MMn, 256, 0, stream>>>(seq, midx, mmask, ws + oEE);
    k_htatt<<<Mr, 256, 0, stream>>>(ws + oEA, hts, ws + oHA);
    // rs = ht_att @ seq[b]
    k_gemm<19,0><<<dim3(20,Bn,3), 256, 0, stream>>>(ws + oHA, nul, nul, Cn, 0, 0,
        seq, nullptr, ws + oRS, Hn, Pn, (long)Cn*Hn);
    // htq = rs @ Wcq + bcq
    k_gemm<16,1><<<dim3(95,1,1), 256, 0, stream>>>(ws + oRS, nul, nul, Hn, 0, 0,
        Wcq, bcq, ws + oHQ, QSn, Mr, 0);
    // ent_key = ent_emb @ Weq + beq
    k_gemm<16,1><<<dim3(115,1,1), 256, 0, stream>>>(ws + oEE, nul, nul, Hn, 0, 0,
        Weq, beq, ws + oEK, QSn, Bn*NEn*MMn, 0);
    k_select<<<dim3(Mr,2), 256, 0, stream>>>(ws + oHQ, ws + oEK, ws + oEE,
        mmask, hts, ws + oSH, ws + oST);
    // hs/ts = tanh([sel|rs] @ W + b)
    k_gemm<16,3><<<dim3(95,1,3), 256, 0, stream>>>(ws + oSH, ws + oRS, nul, Hn, Hn, 0,
        Whe, bhe, ws + oHS, Hn, Mr, 0);
    k_gemm<16,3><<<dim3(95,1,3), 256, 0, stream>>>(ws + oST, ws + oRS, nul, Hn, Hn, 0,
        Wte, bte, ws + oTS, Hn, Mr, 0);
    // bilinear
    k_blinit<<<(Mr*Hn)/256, 256, 0, stream>>>(bbl, ws + oPB);
    if (fast) {
        k_wcvt<<<dim3(768,12), 256, 0, stream>>>(Wbl, Wt);
        k_blmfma<<<dim3(24,3,6), 256, 0, stream>>>(ws + oHS, ws + oTS, Wt, ws + oPB);
    } else {
        k_bilinear_fb<<<dim3(48,1,12), 256, 0, stream>>>(ws + oHS, ws + oTS, Wbl, ws + oPB);
    }
    k_featpp<<<Mr, 256, 0, stream>>>(ws + oPB, pos, hts, ws + oFP);
    k_gemm<16,3><<<dim3(95,1,3), 256, 0, stream>>>(ws + oFP, nul, nul, 1024, 0, 0,
        Wpp, bpp, ws + oPT, Hn, Mr, 0);
    // graph q/k/v
    k_gemm<16,0><<<dim3(95,1,3), 256, 0, stream>>>(ws + oPT, nul, nul, Hn, 0, 0,
        Wgq, nullptr, ws + oQ, Hn, Mr, 0);
    k_gemm<16,4><<<dim3(95,1,3), 256, 0, stream>>>(ws + oPT, nul, nul, Hn, 0, 0,
        Wgk, nullptr, ws + oKT, Hn, Mr, 0);
    k_gemm<16,0><<<dim3(95,1,3), 256, 0, stream>>>(ws + oPT, nul, nul, Hn, 0, 0,
        Wgv, nullptr, ws + oV, Hn, Mr, 0);
    k_graph<<<Mr, 256, 0, stream>>>(ws + oQ, ws + oKT, ws + oV, vis, ws + oPT, ws + oP2);
    // t1 = tanh([hs|ts|pair2] @ Wp1 + bp1)
    k_gemm<16,3><<<dim3(95,1,3), 256, 0, stream>>>(ws + oHS, ws + oTS, ws + oP2,
        Hn, Hn, Hn, Wp1, bp1, ws + oT1, Hn, Mr, 0);
    // logits = t1 @ Wp2 + bp2
    k_gemm<16,1><<<dim3(95,1,1), 256, 0, stream>>>(ws + oT1, nul, nul, Hn, 0, 0,
        Wp2, bp2, out, 97, Mr, 0);
}

// Round 5
// 1202.205 us; speedup vs baseline: 6.6761x; 2.5510x over previous
//
#include <hip/hip_runtime.h>
#include <hip/hip_bf16.h>

#define Bn   4
#define Cn   512
#define Hn   768
#define NHn  12
#define NEn  20
#define MMn  23
#define Pn   380
#define Mr   1520     // B*P
#define QSn  128
#define NEGV (-10000.0f)
#define SCL  0.036084391824351615f   // 1/sqrt(768)

typedef unsigned int uint32;
typedef __attribute__((ext_vector_type(8))) short short8;
typedef __attribute__((ext_vector_type(4))) float float4v;

__device__ __forceinline__ unsigned short f2bs(float f){
    uint32 u = __builtin_bit_cast(uint32, f);
    uint32 r = (u + 0x7FFFu + ((u >> 16) & 1u)) >> 16;   // RNE
    return (unsigned short)r;
}
__device__ __forceinline__ float bs2f(unsigned short s){
    uint32 u = ((uint32)s) << 16;
    return __builtin_bit_cast(float, u);
}
__device__ __forceinline__ uint32 pack2(float a, float b){
    return ((uint32)f2bs(a)) | (((uint32)f2bs(b)) << 16);
}
__device__ __forceinline__ uint32 mulpack(uint32 tv, float hv){
    float lo = bs2f((unsigned short)(tv & 0xFFFFu)) * hv;
    float hi = bs2f((unsigned short)(tv >> 16)) * hv;
    return pack2(lo, hi);
}

// ---------------- ws layout (float offsets) ----------------
// persistent
static const size_t o_HS = 0;          // hs [Mr][768]
static const size_t o_TS = 1167360;    // ts
static const size_t o_PB = 2334720;    // bilinear acc
static const size_t Xo   = 3502080;    // time-shared region, 18,874,368 floats
// early scratch (dies by end of Wte gemm)
static const size_t oEA = Xo;           // 491520
static const size_t oEE = Xo+491520;    // 1413120
static const size_t oEK = Xo+1904640;   // 235520
static const size_t oHA = Xo+2140160;   // 778240
static const size_t oHQ = Xo+2918400;   // 194560
static const size_t oSH = Xo+3112960;   // 1167360
static const size_t oST = Xo+4280320;   // 1167360
static const size_t oRS = Xo+5447680;   // 1167360
// weight^T bf16 regions (float offsets; cast to ushort*)
static const size_t oWCQ = Xo;          // after htatt (over dead EA), 49152 f
static const size_t oWEQ = Xo+49152;    // 49152 f
static const size_t oWHE = Xo;          // after select, 589824 f
static const size_t oWTE = Xo+589824;   // 589824 f (ends < oSH)
static const size_t oWBL = Xo;          // after Wte act, 18,874,368 f (all of X)
// late scratch (after blmfma, over dead WblT)
static const size_t oFP = Xo;           // 1556480
static const size_t oPT = Xo+1556480;
static const size_t oQ  = Xo+2723840;
static const size_t oKT = Xo+3891200;
static const size_t oV  = Xo+5058560;
static const size_t oP2 = Xo+6225920;
static const size_t oT1 = Xo+7393280;   // ends Xo+8560640
static const size_t oWPP = Xo+8560640;  // 393216 f
static const size_t oWGQ = Xo+8953856;  // 294912 f
static const size_t oWGK = Xo+9248768;
static const size_t oWGV = Xo+9543680;
static const size_t oWP1 = Xo+9838592;  // 884736 f
static const size_t oWP2 = Xo+10723328; // 49152 f  (ends Xo+10772480 <= Xo+18874368)
// total = 22,376,448 floats = 89,505,792 B

// ---------------- front-end ----------------

__global__ __launch_bounds__(256) void k_ent_att(const float* __restrict__ att,
    const int* __restrict__ midx, const float* __restrict__ mmask, float* __restrict__ ea)
{
    int x = blockIdx.x;
    int nh = x % NHn; int e = (x / NHn) % NEn; int b = x / (NHn * NEn);
    __shared__ int   sidx[MMn];
    __shared__ float smsk[MMn];
    int t = threadIdx.x;
    if (t < MMn) { sidx[t] = midx[(b*NEn+e)*MMn + t]; smsk[t] = mmask[(b*NEn+e)*MMn + t]; }
    __syncthreads();
    float cnt = 0.f;
    for (int m = 0; m < MMn; m++) cnt += smsk[m];
    for (int c = t; c < Cn; c += 256) {
        float acc = 0.f;
        for (int m = 0; m < MMn; m++)
            acc += smsk[m] * att[((size_t)(b*NHn+nh)*Cn + sidx[m])*Cn + c];
        ea[(size_t)x*Cn + c] = acc / cnt;
    }
}

__global__ __launch_bounds__(256) void k_ent_emb(const float* __restrict__ seq,
    const int* __restrict__ midx, const float* __restrict__ mmask, float* __restrict__ ee)
{
    int x = blockIdx.x;
    int b = x / (NEn*MMn);
    int idx = midx[x]; float msk = mmask[x];
    int t = threadIdx.x;
    for (int h = t; h < Hn; h += 256)
        ee[(size_t)x*Hn + h] = msk * seq[((size_t)b*Cn + idx)*Hn + h];
}

__global__ __launch_bounds__(256) void k_htatt(const float* __restrict__ ea,
    const int* __restrict__ hts, float* __restrict__ hta)
{
    int row = blockIdx.x; int b = row / Pn;
    int he = hts[row*2], te = hts[row*2+1];
    __shared__ float sc[Cn];
    __shared__ float red[256];
    int t = threadIdx.x;
    const float* eah = ea + (size_t)(b*NEn+he)*NHn*Cn;
    const float* eat = ea + (size_t)(b*NEn+te)*NHn*Cn;
    for (int c = t; c < Cn; c += 256) {
        float a = 0.f;
        for (int nh = 0; nh < NHn; nh++) a += eah[nh*Cn+c]*eat[nh*Cn+c];
        sc[c] = a * (1.0f/NHn);
    }
    __syncthreads();
    float ps = sc[t] + sc[t+256];
    red[t] = ps; __syncthreads();
    for (int s = 128; s > 0; s >>= 1) { if (t < s) red[t] += red[t+s]; __syncthreads(); }
    float inv = 1.0f/(red[0] + 1e-5f);
    for (int c = t; c < Cn; c += 256) hta[(size_t)row*Cn + c] = sc[c]*inv;
}

// VALU GEMM kept for rs (per-batch fp32 weight = seq)
template<int TILE, int FLAGS>
__global__ __launch_bounds__(256) void k_gemm(
    const float* __restrict__ inA, int KA,
    const float* __restrict__ W, float* __restrict__ outp,
    int N, int rowsPerBatch, long wStride)
{
    __shared__ __align__(16) float lin[TILE][256];
    int t = threadIdx.x;
    int n = blockIdx.z*256 + t;
    int row0 = blockIdx.y*rowsPerBatch + blockIdx.x*TILE;
    const float* Wb = W + (size_t)blockIdx.y*wStride;
    float acc[TILE];
    #pragma unroll
    for (int x = 0; x < TILE; x++) acc[x] = 0.f;
    for (int kc = 0; kc < KA; kc += 256) {
        __syncthreads();
        #pragma unroll
        for (int s = 0; s < TILE; s++) lin[s][t] = inA[(size_t)(row0+s)*KA + kc + t];
        __syncthreads();
        for (int kq = 0; kq < 64; kq++) {
            float w[4];
            #pragma unroll
            for (int j = 0; j < 4; j++)
                w[j] = (n < N) ? Wb[(size_t)(kc+kq*4+j)*N + n] : 0.f;
            #pragma unroll
            for (int r = 0; r < TILE; r++) {
                float4 a = *(const float4*)&lin[r][kq*4];
                acc[r] += a.x*w[0] + a.y*w[1] + a.z*w[2] + a.w*w[3];
            }
        }
    }
    if (n < N) {
        #pragma unroll
        for (int r = 0; r < TILE; r++)
            outp[(size_t)(row0+r)*N + n] = acc[r];
    }
}

__global__ __launch_bounds__(256) void k_select(const float* __restrict__ htq,
    const float* __restrict__ ekey, const float* __restrict__ ee,
    const float* __restrict__ mmask, const int* __restrict__ hts,
    float* __restrict__ selh, float* __restrict__ selt)
{
    int row = blockIdx.x; int side = blockIdx.y;
    int b = row / Pn;
    int e = hts[row*2 + side];
    __shared__ float qv[QSn];
    __shared__ float gsc[MMn];
    __shared__ float ew[MMn];
    int t = threadIdx.x;
    if (t < QSn) qv[t] = htq[(size_t)row*QSn + t];
    __syncthreads();
    if (t < MMn) {
        const float* kr = ekey + ((size_t)(b*NEn+e)*MMn + t)*QSn;
        float g = 0.f;
        for (int qq = 0; qq < QSn; qq++) g += qv[qq]*kr[qq];
        g *= SCL;
        float msk = mmask[(b*NEn+e)*MMn + t];
        gsc[t] = (msk > 0.f) ? g : NEGV;
    }
    __syncthreads();
    float mx = -1e30f;
    for (int m = 0; m < MMn; m++) mx = fmaxf(mx, gsc[m]);
    if (t < MMn) ew[t] = expf(gsc[t] - mx);
    __syncthreads();
    float s = 0.f;
    for (int m = 0; m < MMn; m++) s += ew[m];
    float invs = 1.0f/s;
    float* dst = side ? selt : selh;
    const float* eb = ee + (size_t)(b*NEn+e)*MMn*Hn;
    for (int h = t; h < Hn; h += 256) {
        float o = 0.f;
        for (int m = 0; m < MMn; m++) o += ew[m]*eb[(size_t)m*Hn + h];
        dst[(size_t)row*Hn + h] = o*invs;
    }
}

// ---------------- weight transpose/convert: W[K][N] f32 -> Wt[Npad][K] bf16 ----------------
struct WD { const float* src; unsigned short* dst; int K; int N; int Npad; int t0; };
struct WT8 { WD d[8]; int nd; };

__global__ __launch_bounds__(256) void k_wtr(WT8 tab)
{
    int b = blockIdx.x;
    int i = 0;
    while (i+1 < tab.nd && b >= tab.d[i+1].t0) i++;
    WD d = tab.d[i];
    int tile = b - d.t0;
    int ktiles = d.K >> 6;
    int kt = tile % ktiles, nt = tile / ktiles;
    int k0 = kt*64, n0 = nt*64;
    __shared__ __align__(16) unsigned short tl[64][72];
    int t = threadIdx.x;
    int nl = t & 63, rq = t >> 6;
    #pragma unroll
    for (int r = 0; r < 16; r++) {
        int kl = r*4 + rq;
        float v = (n0+nl < d.N) ? d.src[(size_t)(k0+kl)*d.N + n0 + nl] : 0.f;
        tl[nl][kl] = f2bs(v);
    }
    __syncthreads();
    int nn2 = t >> 2, kk0 = (t & 3) * 16;
    uint4 a = *(const uint4*)&tl[nn2][kk0];
    uint4 bq = *(const uint4*)&tl[nn2][kk0+8];
    uint4* dst = (uint4*)&d.dst[(size_t)(n0+nn2)*d.K + k0 + kk0];
    dst[0] = a; dst[1] = bq;
}

// ---------------- generic MFMA GEMM ----------------
// out[M][N] = A[M][K](f32, up to 3 row-major segments) @ Wt^T (Wt bf16 [Npad][K])
// block: 64m x 64n, 4 waves (wave w covers n-subtile w*16..w*16+16)
// MODE bits: 1 = atomic accumulate (bias pre-init, act later)
//            4 = add bias (direct)
//            8 = transposed store out[b][N][Pn] (direct)
template<int MODE>
__global__ __launch_bounds__(256) void k_gmfma(
    const float* __restrict__ A0, const float* __restrict__ A1, const float* __restrict__ A2,
    int KA, int KB, int KC,
    const unsigned short* __restrict__ Wt,
    const float* __restrict__ bias, float* __restrict__ out,
    int Mtot, int N, int kchunk)
{
    __shared__ __align__(16) unsigned short sa[64][72];
    __shared__ __align__(16) unsigned short sw[64][72];
    int t = threadIdx.x;
    int K = KA + KB + KC;
    int row0 = blockIdx.x * 64;
    int n0 = blockIdx.y * 64;
    int k0 = (MODE & 1) ? blockIdx.z * kchunk : 0;
    int k1 = (MODE & 1) ? k0 + kchunk : K;
    int lane = t & 63, w = t >> 6, ln = lane & 15, q = lane >> 4;
    int sr = t >> 2;                 // staging row / n index 0..63
    int sk = (t & 3) * 16;           // staging k offset
    int rA = row0 + sr; if (rA > Mtot-1) rA = Mtot-1;

    float4v acc[4];
    #pragma unroll
    for (int mt = 0; mt < 4; mt++) acc[mt] = (float4v)0.f;

    for (int kk = k0; kk < k1; kk += 64) {
        // A segment select (64-window never straddles: all segs multiple of 64)
        const float* src; int kloc, Kl;
        if (kk < KA)            { src = A0; kloc = kk;         Kl = KA; }
        else if (kk < KA + KB)  { src = A1; kloc = kk - KA;    Kl = KB; }
        else                    { src = A2; kloc = kk - KA - KB; Kl = KC; }
        const float* ap = &src[(size_t)rA*Kl + kloc + sk];
        float4 v0 = ((const float4*)ap)[0];
        float4 v1 = ((const float4*)ap)[1];
        float4 v2 = ((const float4*)ap)[2];
        float4 v3 = ((const float4*)ap)[3];
        const uint4* gw = (const uint4*)&Wt[(size_t)(n0+sr)*K + kk + sk];
        uint4 w0 = gw[0], w1 = gw[1];
        uint4 pa, pb;
        pa.x = pack2(v0.x, v0.y); pa.y = pack2(v0.z, v0.w);
        pa.z = pack2(v1.x, v1.y); pa.w = pack2(v1.z, v1.w);
        pb.x = pack2(v2.x, v2.y); pb.y = pack2(v2.z, v2.w);
        pb.z = pack2(v3.x, v3.y); pb.w = pack2(v3.z, v3.w);
        *(uint4*)&sa[sr][sk]   = pa;
        *(uint4*)&sa[sr][sk+8] = pb;
        *(uint4*)&sw[sr][sk]   = w0;
        *(uint4*)&sw[sr][sk+8] = w1;
        __syncthreads();
        short8 b0 = *(const short8*)&sw[w*16+ln][q*8];
        short8 b1 = *(const short8*)&sw[w*16+ln][32 + q*8];
        #pragma unroll
        for (int mt = 0; mt < 4; mt++) {
            short8 a0 = *(const short8*)&sa[mt*16+ln][q*8];
            short8 a1 = *(const short8*)&sa[mt*16+ln][32 + q*8];
            acc[mt] = __builtin_amdgcn_mfma_f32_16x16x32_bf16(a0, b0, acc[mt], 0, 0, 0);
            acc[mt] = __builtin_amdgcn_mfma_f32_16x16x32_bf16(a1, b1, acc[mt], 0, 0, 0);
        }
        __syncthreads();
    }
    // D: row(m) = (lane>>4)*4 + r  (A-operand index), col(n) = lane&15 (B/W index)
    int nn = n0 + w*16 + ln;
    if (nn >= N) return;
    float bv = (MODE & 4) ? bias[nn] : 0.f;
    #pragma unroll
    for (int mt = 0; mt < 4; mt++) {
        #pragma unroll
        for (int r = 0; r < 4; r++) {
            int row = row0 + mt*16 + q*4 + r;
            if (row >= Mtot) continue;
            float val = acc[mt][r];
            if (MODE & 1) {
                atomicAdd(&out[(size_t)row*N + nn], val);
            } else if (MODE & 8) {
                int bb = row / Pn, pp = row % Pn;
                out[((size_t)bb*N + nn)*Pn + pp] = val;
            } else {
                out[(size_t)row*N + nn] = val + bv;
            }
        }
    }
}

__global__ __launch_bounds__(256) void k_binit(const float* __restrict__ bias,
    float* __restrict__ o, int N)
{
    int idx = blockIdx.x*256 + threadIdx.x;
    o[idx] = bias[idx % N];
}

__global__ __launch_bounds__(256) void k_act(float* __restrict__ x)
{
    int idx = blockIdx.x*256 + threadIdx.x;
    x[idx] = tanhf(x[idx]);
}

// ---------------- bilinear MFMA (verified round 4) ----------------
__global__ __launch_bounds__(256,2) void k_blmfma(const float* __restrict__ hs,
    const float* __restrict__ ts, const unsigned short* __restrict__ Wt,
    float* __restrict__ pb)
{
    __shared__ unsigned short hsl[2][64][72];
    __shared__ unsigned short tsl[2][64][72];
    __shared__ unsigned short ap[64][136];
    int t = threadIdx.x;
    int p0 = blockIdx.x * 64;
    int d0 = blockIdx.y * 256;
    int g  = blockIdx.z;
    int lane = t & 63;
    int w = t >> 6;
    int ln = lane & 15, q = lane >> 4;
    {
        int p = t & 63; int c0 = (t >> 6) * 16;
        int pr = p0 + p; if (pr > Mr-1) pr = Mr-1;
        for (int nn = 0; nn < 2; nn++) {
            int n = 2*g + nn;
            const float* hp = hs + (size_t)pr*Hn + n*64 + c0;
            const float* tp = ts + (size_t)pr*Hn + n*64 + c0;
            #pragma unroll
            for (int c = 0; c < 16; c++) {
                hsl[nn][p][c0+c] = f2bs(hp[c]);
                tsl[nn][p][c0+c] = f2bs(tp[c]);
            }
        }
    }
    float4v acc[4][4];
    #pragma unroll
    for (int e = 0; e < 4; e++)
        #pragma unroll
        for (int f = 0; f < 4; f++) acc[e][f] = (float4v)0.f;
    const unsigned short* WtW = Wt + (size_t)(d0 + w*64)*49152;

    for (int nn = 0; nn < 2; nn++) {
        int n = 2*g + nn;
        for (int i0 = 0; i0 < 64; i0 += 2) {
            __syncthreads();
            {
                int p = t & 63, seg = t >> 6;
                int ii = seg >> 1, j0 = (seg & 1) * 32;
                float hv = bs2f(hsl[nn][p][i0+ii]);
                const uint4* tsrc = (const uint4*)&tsl[nn][p][j0];
                uint4* dstp = (uint4*)&ap[p][ii*64 + j0];
                #pragma unroll
                for (int u = 0; u < 4; u++) {
                    uint4 tv = tsrc[u];
                    uint4 o;
                    o.x = mulpack(tv.x, hv); o.y = mulpack(tv.y, hv);
                    o.z = mulpack(tv.z, hv); o.w = mulpack(tv.w, hv);
                    dstp[u] = o;
                }
            }
            __syncthreads();
            size_t kbase = (size_t)n*4096 + (size_t)i0*64;
            #pragma unroll
            for (int c = 0; c < 4; c++) {
                short8 a[4], b[4];
                #pragma unroll
                for (int f = 0; f < 4; f++)
                    a[f] = *(const short8*)&WtW[(size_t)(f*16 + ln)*49152 + kbase + c*32 + q*8];
                #pragma unroll
                for (int e = 0; e < 4; e++)
                    b[e] = *(const short8*)&ap[e*16 + ln][c*32 + q*8];
                #pragma unroll
                for (int e = 0; e < 4; e++)
                    #pragma unroll
                    for (int f = 0; f < 4; f++)
                        acc[e][f] = __builtin_amdgcn_mfma_f32_16x16x32_bf16(a[f], b[e], acc[e][f], 0, 0, 0);
            }
        }
    }
    for (int e = 0; e < 4; e++) {
        int p = p0 + e*16 + ln;
        if (p >= Mr) continue;
        for (int f = 0; f < 4; f++) {
            int dbase = d0 + w*64 + f*16 + q*4;
            #pragma unroll
            for (int r = 0; r < 4; r++)
                atomicAdd(&pb[(size_t)p*Hn + dbase + r], acc[e][f][r]);
        }
    }
}

// ---------------- back-end ----------------

__global__ __launch_bounds__(256) void k_featpp(const float* __restrict__ pairbl,
    const float* __restrict__ pos, const int* __restrict__ hts, float* __restrict__ fpp)
{
    int row = blockIdx.x; int t = threadIdx.x;
    int he = hts[row*2], te = hts[row*2+1];
    float* dst = fpp + (size_t)row*1024;
    if (t < 128) { dst[t] = pos[he*128 + t]; dst[896 + t] = pos[te*128 + t]; }
    for (int h = t; h < Hn; h += 256) dst[128 + h] = pairbl[(size_t)row*Hn + h];
}

__global__ __launch_bounds__(256) void k_graph(const float* __restrict__ q,
    const float* __restrict__ kT, const float* __restrict__ v, const float* __restrict__ vis,
    const float* __restrict__ pairT, float* __restrict__ pair2)
{
    int row = blockIdx.x; int b = row / Pn; int p = row % Pn;
    __shared__ float qs[Hn];
    __shared__ float sc[Pn];
    __shared__ float red[256];
    int t = threadIdx.x;
    for (int h = t; h < Hn; h += 256) qs[h] = q[(size_t)row*Hn + h];
    __syncthreads();
    for (int qq = t; qq < Pn; qq += 256) {
        const float* kcol = kT + (size_t)b*Hn*Pn + qq;
        float a = 0.f;
        for (int h = 0; h < Hn; h++) a += qs[h]*kcol[(size_t)h*Pn];
        a *= SCL;
        float ms = vis[((size_t)b*Pn + p)*Pn + qq];
        sc[qq] = (ms > 0.f) ? a : NEGV;
    }
    __syncthreads();
    float mx = -1e30f;
    for (int qq = t; qq < Pn; qq += 256) mx = fmaxf(mx, sc[qq]);
    red[t] = mx; __syncthreads();
    for (int s = 128; s > 0; s >>= 1) { if (t < s) red[t] = fmaxf(red[t], red[t+s]); __syncthreads(); }
    mx = red[0];
    __syncthreads();
    float ps = 0.f;
    for (int qq = t; qq < Pn; qq += 256) { float e2 = expf(sc[qq]-mx); sc[qq] = e2; ps += e2; }
    red[t] = ps; __syncthreads();
    for (int s = 128; s > 0; s >>= 1) { if (t < s) red[t] += red[t+s]; __syncthreads(); }
    float invs = 1.0f/red[0];
    __syncthreads();
    for (int d = t; d < Hn; d += 256) {
        float o = 0.f;
        for (int qq = 0; qq < Pn; qq++) o += sc[qq]*v[((size_t)b*Pn+qq)*Hn + d];
        pair2[(size_t)row*Hn + d] = pairT[(size_t)row*Hn + d] + o*invs;
    }
}

__global__ __launch_bounds__(256) void k_fillu(unsigned int* p, unsigned int v, int n){
    int i = blockIdx.x*256 + threadIdx.x;
    if (i < n) p[i] = v;
}

// ---------------- launch ----------------
extern "C" void kernel_launch(void* const* d_in, const int* in_sizes, int n_in,
                              void* d_out, int out_size, void* d_ws, size_t ws_size,
                              hipStream_t stream)
{
    const float* seq  = (const float*)d_in[0];
    const float* att  = (const float*)d_in[1];
    const int*   midx = (const int*)d_in[2];
    const float* mmask= (const float*)d_in[3];
    const int*   hts  = (const int*)d_in[4];
    const float* vis  = (const float*)d_in[5];
    const float* Wcq = (const float*)d_in[6];  const float* bcq = (const float*)d_in[7];
    const float* Weq = (const float*)d_in[8];  const float* beq = (const float*)d_in[9];
    const float* Whe = (const float*)d_in[10]; const float* bhe = (const float*)d_in[11];
    const float* Wte = (const float*)d_in[12]; const float* bte = (const float*)d_in[13];
    const float* Wbl = (const float*)d_in[14]; const float* bbl = (const float*)d_in[15];
    const float* Wpp = (const float*)d_in[16]; const float* bpp = (const float*)d_in[17];
    const float* Wgq = (const float*)d_in[18];
    const float* Wgk = (const float*)d_in[19];
    const float* Wgv = (const float*)d_in[20];
    const float* Wp1 = (const float*)d_in[21]; const float* bp1 = (const float*)d_in[22];
    const float* Wp2 = (const float*)d_in[23]; const float* bp2 = (const float*)d_in[24];
    const float* pos = (const float*)d_in[25];
    float* ws = (float*)d_ws;
    float* out = (float*)d_out;
    const float* nul = nullptr;

    if (ws_size < 89505792ULL) {   // sentinel (shouldn't happen: round-4 proved >=)
        int n = out_size/2;
        k_fillu<<<(n+255)/256, 256, 0, stream>>>((unsigned int*)d_out, 0x476A476Au, n);
        return;
    }

    unsigned short* WCQt = (unsigned short*)(ws + oWCQ);
    unsigned short* WEQt = (unsigned short*)(ws + oWEQ);
    unsigned short* WHEt = (unsigned short*)(ws + oWHE);
    unsigned short* WTEt = (unsigned short*)(ws + oWTE);
    unsigned short* WBLt = (unsigned short*)(ws + oWBL);
    unsigned short* WPPt = (unsigned short*)(ws + oWPP);
    unsigned short* WGQt = (unsigned short*)(ws + oWGQ);
    unsigned short* WGKt = (unsigned short*)(ws + oWGK);
    unsigned short* WGVt = (unsigned short*)(ws + oWGV);
    unsigned short* WP1t = (unsigned short*)(ws + oWP1);
    unsigned short* WP2t = (unsigned short*)(ws + oWP2);

    // ---- front-end ----
    k_ent_att<<<Bn*NEn*NHn, 256, 0, stream>>>(att, midx, mmask, ws + oEA);
    k_ent_emb<<<Bn*NEn*MMn, 256, 0, stream>>>(seq, midx, mmask, ws + oEE);
    k_htatt<<<Mr, 256, 0, stream>>>(ws + oEA, hts, ws + oHA);

    // Wcq/Weq -> bf16 T (into dead EA region)
    {
        WT8 tb{}; tb.nd = 2;
        tb.d[0] = { Wcq, WCQt, 768, 128, 128, 0 };
        tb.d[1] = { Weq, WEQt, 768, 128, 128, 24 };
        k_wtr<<<48, 256, 0, stream>>>(tb);
    }
    // rs = ht_att @ seq[b]  (VALU, per-batch fp32 weight)
    k_gemm<19,0><<<dim3(20,Bn,3), 256, 0, stream>>>(ws + oHA, Cn, seq, ws + oRS,
        Hn, Pn, (long)Cn*Hn);
    // htq = rs @ Wcq + bcq  (MFMA direct+bias)
    k_gmfma<4><<<dim3(24,2,1), 256, 0, stream>>>(ws + oRS, nul, nul, Hn, 0, 0,
        WCQt, bcq, ws + oHQ, Mr, QSn, Hn);
    // ent_key = ent_emb @ Weq + beq
    k_gmfma<4><<<dim3(29,2,1), 256, 0, stream>>>(ws + oEE, nul, nul, Hn, 0, 0,
        WEQt, beq, ws + oEK, Bn*NEn*MMn, QSn, Hn);
    k_select<<<dim3(Mr,2), 256, 0, stream>>>(ws + oHQ, ws + oEK, ws + oEE,
        mmask, hts, ws + oSH, ws + oST);

    // Whe/Wte -> bf16 T (early scratch EA..HQ now dead)
    {
        WT8 tb{}; tb.nd = 2;
        tb.d[0] = { Whe, WHEt, 1536, 768, 768, 0 };
        tb.d[1] = { Wte, WTEt, 1536, 768, 768, 288 };
        k_wtr<<<576, 256, 0, stream>>>(tb);
    }
    // hs = tanh([selh|rs] @ Whe + bhe): bias-init, atomic k-split x3, tanh
    k_binit<<<(Mr*Hn)/256, 256, 0, stream>>>(bhe, ws + o_HS, Hn);
    k_gmfma<1><<<dim3(24,12,3), 256, 0, stream>>>(ws + oSH, ws + oRS, nul, Hn, Hn, 0,
        WHEt, nul, ws + o_HS, Mr, Hn, 512);
    k_act<<<(Mr*Hn)/256, 256, 0, stream>>>(ws + o_HS);
    k_binit<<<(Mr*Hn)/256, 256, 0, stream>>>(bte, ws + o_TS, Hn);
    k_gmfma<1><<<dim3(24,12,3), 256, 0, stream>>>(ws + oST, ws + oRS, nul, Hn, Hn, 0,
        WTEt, nul, ws + o_TS, Mr, Hn, 512);
    k_act<<<(Mr*Hn)/256, 256, 0, stream>>>(ws + o_TS);

    // bilinear: Wbl -> bf16 T (whole X now dead), init, MFMA
    {
        WT8 tb{}; tb.nd = 1;
        tb.d[0] = { Wbl, WBLt, 49152, 768, 768, 0 };
        k_wtr<<<9216, 256, 0, stream>>>(tb);
    }
    k_binit<<<(Mr*Hn)/256, 256, 0, stream>>>(bbl, ws + o_PB, Hn);
    k_blmfma<<<dim3(24,3,6), 256, 0, stream>>>(ws + o_HS, ws + o_TS, WBLt, ws + o_PB);

    k_featpp<<<Mr, 256, 0, stream>>>(ws + o_PB, pos, hts, ws + oFP);

    // late weights -> bf16 T (over dead WblT tail)
    {
        WT8 tb{}; tb.nd = 6;
        tb.d[0] = { Wpp, WPPt, 1024, 768, 768, 0 };
        tb.d[1] = { Wgq, WGQt, 768, 768, 768, 192 };
        tb.d[2] = { Wgk, WGKt, 768, 768, 768, 336 };
        tb.d[3] = { Wgv, WGVt, 768, 768, 768, 480 };
        tb.d[4] = { Wp1, WP1t, 2304, 768, 768, 624 };
        tb.d[5] = { Wp2, WP2t, 768, 97, 128, 1056 };
        k_wtr<<<1080, 256, 0, stream>>>(tb);
    }
    // pairT = tanh(fpp @ Wpp + bpp)
    k_binit<<<(Mr*Hn)/256, 256, 0, stream>>>(bpp, ws + oPT, Hn);
    k_gmfma<1><<<dim3(24,12,2), 256, 0, stream>>>(ws + oFP, nul, nul, 1024, 0, 0,
        WPPt, nul, ws + oPT, Mr, Hn, 512);
    k_act<<<(Mr*Hn)/256, 256, 0, stream>>>(ws + oPT);
    // q / kT / v
    k_gmfma<0><<<dim3(24,12,1), 256, 0, stream>>>(ws + oPT, nul, nul, Hn, 0, 0,
        WGQt, nul, ws + oQ, Mr, Hn, Hn);
    k_gmfma<8><<<dim3(24,12,1), 256, 0, stream>>>(ws + oPT, nul, nul, Hn, 0, 0,
        WGKt, nul, ws + oKT, Mr, Hn, Hn);
    k_gmfma<0><<<dim3(24,12,1), 256, 0, stream>>>(ws + oPT, nul, nul, Hn, 0, 0,
        WGVt, nul, ws + oV, Mr, Hn, Hn);
    k_graph<<<Mr, 256, 0, stream>>>(ws + oQ, ws + oKT, ws + oV, vis, ws + oPT, ws + oP2);
    // t1 = tanh([hs|ts|pair2] @ Wp1 + bp1)
    k_binit<<<(Mr*Hn)/256, 256, 0, stream>>>(bp1, ws + oT1, Hn);
    k_gmfma<1><<<dim3(24,12,3), 256, 0, stream>>>(ws + o_HS, ws + o_TS, ws + oP2,
        Hn, Hn, Hn, WP1t, nul, ws + oT1, Mr, Hn, 768);
    k_act<<<(Mr*Hn)/256, 256, 0, stream>>>(ws + oT1);
    // logits = t1 @ Wp2 + bp2 -> d_out (fp32)
    k_gmfma<4><<<dim3(24,2,1), 256, 0, stream>>>(ws + oT1, nul, nul, Hn, 0, 0,
        WP2t, bp2, out, Mr, 97, Hn);
}

// Round 6
// 1070.747 us; speedup vs baseline: 7.4957x; 1.1228x over previous
//
#include <hip/hip_runtime.h>
#include <hip/hip_bf16.h>

#define Bn   4
#define Cn   512
#define Hn   768
#define NHn  12
#define NEn  20
#define MMn  23
#define Pn   380
#define Mr   1520     // B*P
#define QSn  128
#define NEGV (-10000.0f)
#define SCL  0.036084391824351615f   // 1/sqrt(768)

typedef unsigned int uint32;
typedef __attribute__((ext_vector_type(8))) short short8;
typedef __attribute__((ext_vector_type(4))) float float4v;

__device__ __forceinline__ unsigned short f2bs(float f){
    uint32 u = __builtin_bit_cast(uint32, f);
    uint32 r = (u + 0x7FFFu + ((u >> 16) & 1u)) >> 16;   // RNE
    return (unsigned short)r;
}
__device__ __forceinline__ float bs2f(unsigned short s){
    uint32 u = ((uint32)s) << 16;
    return __builtin_bit_cast(float, u);
}
__device__ __forceinline__ uint32 pack2(float a, float b){
    return ((uint32)f2bs(a)) | (((uint32)f2bs(b)) << 16);
}
__device__ __forceinline__ uint32 mulpack(uint32 tv, float hv){
    float lo = bs2f((unsigned short)(tv & 0xFFFFu)) * hv;
    float hi = bs2f((unsigned short)(tv >> 16)) * hv;
    return pack2(lo, hi);
}

// ---------------- ws layout (float offsets) ----------------
static const size_t o_HS = 0;          // hs-acc [Mr][768]  (raw, tanh at consumers)
static const size_t o_TS = 1167360;    // ts-acc
static const size_t o_PB = 2334720;    // bilinear acc
static const size_t Xo   = 3502080;    // time-shared region, 18,874,368 floats
// early scratch
static const size_t oEA = Xo;           // 491520
static const size_t oEE = Xo+491520;    // 1413120
static const size_t oEK = Xo+1904640;   // 235520
static const size_t oHA = Xo+2140160;   // 778240
static const size_t oHQ = Xo+2918400;   // 194560
static const size_t oSH = Xo+3112960;   // 1167360
static const size_t oST = Xo+4280320;   // 1167360
static const size_t oRS = Xo+5447680;   // 1167360
static const size_t oSEQT = Xo+6615040; // seqT bf16 [B][768][512] = 786432 f
// weight^T bf16 regions (float offsets; cast to ushort*)
static const size_t oWCQ = Xo;          // over dead EA, 49152 f
static const size_t oWEQ = Xo+49152;    // 49152 f
static const size_t oWHE = Xo;          // after select (EA/EE dead), 589824 f
static const size_t oWTE = Xo+589824;   // 589824 f
static const size_t oWBL = Xo;          // after ts-gmfma, all of X
// late scratch (after blmfma, over dead WblT)
static const size_t oFP = Xo;           // 1556480
static const size_t oPT = Xo+1556480;
static const size_t oQ  = Xo+2723840;
static const size_t oKT = Xo+3891200;
static const size_t oV  = Xo+5058560;
static const size_t oP2 = Xo+6225920;
static const size_t oT1 = Xo+7393280;   // ends Xo+8560640
static const size_t oWPP = Xo+8560640;  // 393216 f
static const size_t oWGQ = Xo+8953856;  // 294912 f  (WGQ|WGK|WGV contiguous -> fused qkv)
static const size_t oWGK = Xo+9248768;
static const size_t oWGV = Xo+9543680;
static const size_t oWP1 = Xo+9838592;  // 884736 f
static const size_t oWP2 = Xo+10723328; // 49152 f
// total = 22,376,448 floats = 89,505,792 B

// ---------------- front-end ----------------

__global__ __launch_bounds__(256) void k_ent_att(const float* __restrict__ att,
    const int* __restrict__ midx, const float* __restrict__ mmask, float* __restrict__ ea)
{
    int x = blockIdx.x;
    int nh = x % NHn; int e = (x / NHn) % NEn; int b = x / (NHn * NEn);
    __shared__ int   sidx[MMn];
    __shared__ float smsk[MMn];
    int t = threadIdx.x;
    if (t < MMn) { sidx[t] = midx[(b*NEn+e)*MMn + t]; smsk[t] = mmask[(b*NEn+e)*MMn + t]; }
    __syncthreads();
    float cnt = 0.f;
    for (int m = 0; m < MMn; m++) cnt += smsk[m];
    for (int c = t; c < Cn; c += 256) {
        float acc = 0.f;
        for (int m = 0; m < MMn; m++)
            acc += smsk[m] * att[((size_t)(b*NHn+nh)*Cn + sidx[m])*Cn + c];
        ea[(size_t)x*Cn + c] = acc / cnt;
    }
}

__global__ __launch_bounds__(256) void k_ent_emb(const float* __restrict__ seq,
    const int* __restrict__ midx, const float* __restrict__ mmask, float* __restrict__ ee)
{
    int x = blockIdx.x;
    int b = x / (NEn*MMn);
    int idx = midx[x]; float msk = mmask[x];
    int t = threadIdx.x;
    for (int h = t; h < Hn; h += 256)
        ee[(size_t)x*Hn + h] = msk * seq[((size_t)b*Cn + idx)*Hn + h];
}

__global__ __launch_bounds__(256) void k_htatt(const float* __restrict__ ea,
    const int* __restrict__ hts, float* __restrict__ hta)
{
    int row = blockIdx.x; int b = row / Pn;
    int he = hts[row*2], te = hts[row*2+1];
    __shared__ float sc[Cn];
    __shared__ float red[256];
    int t = threadIdx.x;
    const float* eah = ea + (size_t)(b*NEn+he)*NHn*Cn;
    const float* eat = ea + (size_t)(b*NEn+te)*NHn*Cn;
    for (int c = t; c < Cn; c += 256) {
        float a = 0.f;
        for (int nh = 0; nh < NHn; nh++) a += eah[nh*Cn+c]*eat[nh*Cn+c];
        sc[c] = a * (1.0f/NHn);
    }
    __syncthreads();
    float ps = sc[t] + sc[t+256];
    red[t] = ps; __syncthreads();
    for (int s = 128; s > 0; s >>= 1) { if (t < s) red[t] += red[t+s]; __syncthreads(); }
    float inv = 1.0f/(red[0] + 1e-5f);
    for (int c = t; c < Cn; c += 256) hta[(size_t)row*Cn + c] = sc[c]*inv;
}

__global__ __launch_bounds__(256) void k_select(const float* __restrict__ htq,
    const float* __restrict__ ekey, const float* __restrict__ ee,
    const float* __restrict__ mmask, const int* __restrict__ hts,
    float* __restrict__ selh, float* __restrict__ selt)
{
    int row = blockIdx.x; int side = blockIdx.y;
    int b = row / Pn;
    int e = hts[row*2 + side];
    __shared__ float qv[QSn];
    __shared__ float gsc[MMn];
    __shared__ float ew[MMn];
    int t = threadIdx.x;
    if (t < QSn) qv[t] = htq[(size_t)row*QSn + t];
    __syncthreads();
    if (t < MMn) {
        const float* kr = ekey + ((size_t)(b*NEn+e)*MMn + t)*QSn;
        float g = 0.f;
        for (int qq = 0; qq < QSn; qq++) g += qv[qq]*kr[qq];
        g *= SCL;
        float msk = mmask[(b*NEn+e)*MMn + t];
        gsc[t] = (msk > 0.f) ? g : NEGV;
    }
    __syncthreads();
    float mx = -1e30f;
    for (int m = 0; m < MMn; m++) mx = fmaxf(mx, gsc[m]);
    if (t < MMn) ew[t] = expf(gsc[t] - mx);
    __syncthreads();
    float s = 0.f;
    for (int m = 0; m < MMn; m++) s += ew[m];
    float invs = 1.0f/s;
    float* dst = side ? selt : selh;
    const float* eb = ee + (size_t)(b*NEn+e)*MMn*Hn;
    for (int h = t; h < Hn; h += 256) {
        float o = 0.f;
        for (int m = 0; m < MMn; m++) o += ew[m]*eb[(size_t)m*Hn + h];
        dst[(size_t)row*Hn + h] = o*invs;
    }
}

// ---------------- weight transpose/convert: W[K][N] f32 -> Wt[Npad][K] bf16 ----------------
struct WD { const float* src; unsigned short* dst; int K; int N; int Npad; int t0; };
struct WT8 { WD d[8]; int nd; };

__global__ __launch_bounds__(256) void k_wtr(WT8 tab)
{
    int b = blockIdx.x;
    int i = 0;
    while (i+1 < tab.nd && b >= tab.d[i+1].t0) i++;
    WD d = tab.d[i];
    int tile = b - d.t0;
    int ktiles = d.K >> 6;
    int kt = tile % ktiles, nt = tile / ktiles;
    int k0 = kt*64, n0 = nt*64;
    __shared__ __align__(16) unsigned short tl[64][72];
    int t = threadIdx.x;
    int nl = t & 63, rq = t >> 6;
    #pragma unroll
    for (int r = 0; r < 16; r++) {
        int kl = r*4 + rq;
        float v = (n0+nl < d.N) ? d.src[(size_t)(k0+kl)*d.N + n0 + nl] : 0.f;
        tl[nl][kl] = f2bs(v);
    }
    __syncthreads();
    int nn2 = t >> 2, kk0 = (t & 3) * 16;
    uint4 a = *(const uint4*)&tl[nn2][kk0];
    uint4 bq = *(const uint4*)&tl[nn2][kk0+8];
    uint4* dst = (uint4*)&d.dst[(size_t)(n0+nn2)*d.K + k0 + kk0];
    dst[0] = a; dst[1] = bq;
}

// ---------------- generic MFMA GEMM ----------------
// out[M][N] = A[M][K](f32, up to 3 segments) @ Wt^T (Wt bf16 [Npad][K])
// MODE bits: 1=atomic accumulate (k-split over z; bias pre-init), 4=+bias,
//            16=qkv routing (out=q, out2=kT transposed, out3=v; N=2304),
//            32=batched over z (aStride/wStride/oStride)
// TM: tanh applied to A-segment s when (TM>>s)&1
template<int MODE, int TM>
__global__ __launch_bounds__(256,4) void k_gmfma(
    const float* __restrict__ A0, const float* __restrict__ A1, const float* __restrict__ A2,
    int KA, int KB, int KC,
    const unsigned short* __restrict__ Wt,
    const float* __restrict__ bias, float* __restrict__ out,
    float* __restrict__ out2, float* __restrict__ out3,
    int Mtot, int N, int kchunk,
    long aStride, long wStride, long oStride)
{
    __shared__ __align__(16) unsigned short sa[64][72];
    __shared__ __align__(16) unsigned short sw[64][72];
    int t = threadIdx.x;
    int K = KA + KB + KC;
    int row0 = blockIdx.x * 64;
    int n0 = blockIdx.y * 64;
    int bz = blockIdx.z;
    const float* Ab = A0; const unsigned short* W = Wt; float* O = out;
    if (MODE & 32) { Ab += (size_t)bz*aStride; W += (size_t)bz*wStride; O += (size_t)bz*oStride; }
    int k0 = 0, k1 = K;
    if (MODE & 1) { k0 = bz*kchunk; k1 = k0 + kchunk; }
    int lane = t & 63, w = t >> 6, ln = lane & 15, q = lane >> 4;
    int sr = t >> 2;
    int sk = (t & 3) * 16;
    int rA = row0 + sr; if (rA > Mtot-1) rA = Mtot-1;

    float4v acc[4];
    #pragma unroll
    for (int mt = 0; mt < 4; mt++) acc[mt] = (float4v)0.f;

    for (int kk = k0; kk < k1; kk += 64) {
        const float* src; int kloc, Kl, seg;
        if (kk < KA)            { src = Ab; kloc = kk;          Kl = KA; seg = 0; }
        else if (kk < KA + KB)  { src = A1; kloc = kk - KA;     Kl = KB; seg = 1; }
        else                    { src = A2; kloc = kk - KA - KB; Kl = KC; seg = 2; }
        const float* ap = &src[(size_t)rA*Kl + kloc + sk];
        float4 v0 = ((const float4*)ap)[0];
        float4 v1 = ((const float4*)ap)[1];
        float4 v2 = ((const float4*)ap)[2];
        float4 v3 = ((const float4*)ap)[3];
        if (TM && ((TM >> seg) & 1)) {
            v0.x = tanhf(v0.x); v0.y = tanhf(v0.y); v0.z = tanhf(v0.z); v0.w = tanhf(v0.w);
            v1.x = tanhf(v1.x); v1.y = tanhf(v1.y); v1.z = tanhf(v1.z); v1.w = tanhf(v1.w);
            v2.x = tanhf(v2.x); v2.y = tanhf(v2.y); v2.z = tanhf(v2.z); v2.w = tanhf(v2.w);
            v3.x = tanhf(v3.x); v3.y = tanhf(v3.y); v3.z = tanhf(v3.z); v3.w = tanhf(v3.w);
        }
        const uint4* gw = (const uint4*)&W[(size_t)(n0+sr)*K + kk + sk];
        uint4 w0 = gw[0], w1 = gw[1];
        uint4 pa, pb;
        pa.x = pack2(v0.x, v0.y); pa.y = pack2(v0.z, v0.w);
        pa.z = pack2(v1.x, v1.y); pa.w = pack2(v1.z, v1.w);
        pb.x = pack2(v2.x, v2.y); pb.y = pack2(v2.z, v2.w);
        pb.z = pack2(v3.x, v3.y); pb.w = pack2(v3.z, v3.w);
        *(uint4*)&sa[sr][sk]   = pa;
        *(uint4*)&sa[sr][sk+8] = pb;
        *(uint4*)&sw[sr][sk]   = w0;
        *(uint4*)&sw[sr][sk+8] = w1;
        __syncthreads();
        short8 b0 = *(const short8*)&sw[w*16+ln][q*8];
        short8 b1 = *(const short8*)&sw[w*16+ln][32 + q*8];
        #pragma unroll
        for (int mt = 0; mt < 4; mt++) {
            short8 a0 = *(const short8*)&sa[mt*16+ln][q*8];
            short8 a1 = *(const short8*)&sa[mt*16+ln][32 + q*8];
            acc[mt] = __builtin_amdgcn_mfma_f32_16x16x32_bf16(a0, b0, acc[mt], 0, 0, 0);
            acc[mt] = __builtin_amdgcn_mfma_f32_16x16x32_bf16(a1, b1, acc[mt], 0, 0, 0);
        }
        __syncthreads();
    }
    // D: row(m) = (lane>>4)*4+r (A row), col(n) = lane&15 (W row)
    int nn = n0 + w*16 + ln;
    if (MODE & 16) {
        int sg = nn / Hn; int nl = nn - sg*Hn;
        #pragma unroll
        for (int mt = 0; mt < 4; mt++) {
            #pragma unroll
            for (int r = 0; r < 4; r++) {
                int row = row0 + mt*16 + q*4 + r;
                if (row >= Mtot) continue;
                float val = acc[mt][r];
                if (sg == 0)      out [(size_t)row*Hn + nl] = val;
                else if (sg == 2) out3[(size_t)row*Hn + nl] = val;
                else {
                    int bb = row / Pn, pp = row % Pn;
                    out2[((size_t)bb*Hn + nl)*Pn + pp] = val;
                }
            }
        }
        return;
    }
    if (nn >= N) return;
    float bv = (MODE & 4) ? bias[nn] : 0.f;
    #pragma unroll
    for (int mt = 0; mt < 4; mt++) {
        #pragma unroll
        for (int r = 0; r < 4; r++) {
            int row = row0 + mt*16 + q*4 + r;
            if (row >= Mtot) continue;
            float val = acc[mt][r];
            if (MODE & 1) atomicAdd(&O[(size_t)row*N + nn], val);
            else          O[(size_t)row*N + nn] = val + bv;
        }
    }
}

__global__ __launch_bounds__(256) void k_binit(const float* __restrict__ bias,
    float* __restrict__ o, int N)
{
    int idx = blockIdx.x*256 + threadIdx.x;
    o[idx] = bias[idx % N];
}

__global__ __launch_bounds__(256) void k_binit3(const float* __restrict__ b0,
    const float* __restrict__ b1, const float* __restrict__ b2, float* __restrict__ o)
{
    int idx = blockIdx.x*256 + threadIdx.x;   // < 3*Mr*Hn
    int r = idx / (Mr*Hn);
    const float* bb = (r == 0) ? b0 : ((r == 1) ? b1 : b2);
    o[idx] = bb[idx % Hn];
}

// ---------------- bilinear MFMA v2: 4 blocks/CU, d-tile 128, tanh-fused staging ----------------
__global__ __launch_bounds__(256,4) void k_blmfma(const float* __restrict__ hs,
    const float* __restrict__ ts, const unsigned short* __restrict__ Wt,
    float* __restrict__ pb)
{
    __shared__ __align__(16) unsigned short hsl[64][72];
    __shared__ __align__(16) unsigned short tsl[64][72];
    __shared__ __align__(16) unsigned short ap[64][136];
    int t = threadIdx.x;
    int p0 = blockIdx.x * 64;        // 24
    int d0 = blockIdx.y * 128;       // 6
    int g  = blockIdx.z;             // 6 -> n = 2g, 2g+1
    int lane = t & 63, w = t >> 6, ln = lane & 15, q = lane >> 4;
    float4v acc[4][2];
    #pragma unroll
    for (int e = 0; e < 4; e++)
        #pragma unroll
        for (int f = 0; f < 2; f++) acc[e][f] = (float4v)0.f;
    const unsigned short* WtW = Wt + (size_t)(d0 + w*32)*49152;

    for (int nn = 0; nn < 2; nn++) {
        int n = 2*g + nn;
        {   // stage hs/ts (tanh fused) for this n
            int p = t & 63; int c0 = (t >> 6) * 16;
            int pr = p0 + p; if (pr > Mr-1) pr = Mr-1;
            const float* hp = hs + (size_t)pr*Hn + n*64 + c0;
            const float* tp = ts + (size_t)pr*Hn + n*64 + c0;
            #pragma unroll
            for (int c = 0; c < 16; c++) {
                hsl[p][c0+c] = f2bs(tanhf(hp[c]));
                tsl[p][c0+c] = f2bs(tanhf(tp[c]));
            }
        }
        for (int i0 = 0; i0 < 64; i0 += 2) {
            __syncthreads();
            {   // ap[p][ii*64+j] = hs[p][i0+ii]*ts[p][j]
                int p = t & 63, sg = t >> 6;
                int ii = sg >> 1, j0 = (sg & 1) * 32;
                float hv = bs2f(hsl[p][i0+ii]);
                const uint4* tsrc = (const uint4*)&tsl[p][j0];
                uint4* dstp = (uint4*)&ap[p][ii*64 + j0];
                #pragma unroll
                for (int u = 0; u < 4; u++) {
                    uint4 tv = tsrc[u]; uint4 o;
                    o.x = mulpack(tv.x, hv); o.y = mulpack(tv.y, hv);
                    o.z = mulpack(tv.z, hv); o.w = mulpack(tv.w, hv);
                    dstp[u] = o;
                }
            }
            __syncthreads();
            size_t kbase = (size_t)n*4096 + (size_t)i0*64;
            #pragma unroll
            for (int c = 0; c < 4; c++) {
                short8 a[2], b[4];
                #pragma unroll
                for (int f = 0; f < 2; f++)
                    a[f] = *(const short8*)&WtW[(size_t)(f*16 + ln)*49152 + kbase + c*32 + q*8];
                #pragma unroll
                for (int e = 0; e < 4; e++)
                    b[e] = *(const short8*)&ap[e*16 + ln][c*32 + q*8];
                #pragma unroll
                for (int e = 0; e < 4; e++)
                    #pragma unroll
                    for (int f = 0; f < 2; f++)
                        acc[e][f] = __builtin_amdgcn_mfma_f32_16x16x32_bf16(a[f], b[e], acc[e][f], 0, 0, 0);
            }
        }
        __syncthreads();  // protect hsl/tsl restage vs any wave still in build-read (paranoia, cheap)
    }
    #pragma unroll
    for (int e = 0; e < 4; e++) {
        int p = p0 + e*16 + ln;
        if (p >= Mr) continue;
        #pragma unroll
        for (int f = 0; f < 2; f++) {
            int dbase = d0 + w*32 + f*16 + q*4;
            #pragma unroll
            for (int r = 0; r < 4; r++)
                atomicAdd(&pb[(size_t)p*Hn + dbase + r], acc[e][f][r]);
        }
    }
}

// ---------------- back-end ----------------

__global__ __launch_bounds__(256) void k_featpp(const float* __restrict__ pairbl,
    const float* __restrict__ pos, const int* __restrict__ hts, float* __restrict__ fpp)
{
    int row = blockIdx.x; int t = threadIdx.x;
    int he = hts[row*2], te = hts[row*2+1];
    float* dst = fpp + (size_t)row*1024;
    if (t < 128) { dst[t] = pos[he*128 + t]; dst[896 + t] = pos[te*128 + t]; }
    for (int h = t; h < Hn; h += 256) dst[128 + h] = pairbl[(size_t)row*Hn + h];
}

// pair2 = tanh(pairT) + softmax(q@kT masked) @ v   (V read once; 3 d-chunks in regs)
__global__ __launch_bounds__(256) void k_graph(const float* __restrict__ q,
    const float* __restrict__ kT, const float* __restrict__ v, const float* __restrict__ vis,
    const float* __restrict__ pairT, float* __restrict__ pair2)
{
    int row = blockIdx.x; int b = row / Pn; int p = row % Pn;
    __shared__ float qs[Hn];
    __shared__ float sc[Pn];
    __shared__ float red[256];
    int t = threadIdx.x;
    for (int h = t; h < Hn; h += 256) qs[h] = q[(size_t)row*Hn + h];
    __syncthreads();
    for (int qq = t; qq < Pn; qq += 256) {
        const float* kcol = kT + (size_t)b*Hn*Pn + qq;
        float a = 0.f;
        for (int h = 0; h < Hn; h++) a += qs[h]*kcol[(size_t)h*Pn];
        a *= SCL;
        float ms = vis[((size_t)b*Pn + p)*Pn + qq];
        sc[qq] = (ms > 0.f) ? a : NEGV;
    }
    __syncthreads();
    float mx = -1e30f;
    for (int qq = t; qq < Pn; qq += 256) mx = fmaxf(mx, sc[qq]);
    red[t] = mx; __syncthreads();
    for (int s = 128; s > 0; s >>= 1) { if (t < s) red[t] = fmaxf(red[t], red[t+s]); __syncthreads(); }
    mx = red[0];
    __syncthreads();
    float ps = 0.f;
    for (int qq = t; qq < Pn; qq += 256) { float e2 = expf(sc[qq]-mx); sc[qq] = e2; ps += e2; }
    red[t] = ps; __syncthreads();
    for (int s = 128; s > 0; s >>= 1) { if (t < s) red[t] += red[t+s]; __syncthreads(); }
    float invs = 1.0f/red[0];
    __syncthreads();
    float a0 = 0.f, a1 = 0.f, a2 = 0.f;
    for (int qq = 0; qq < Pn; qq++) {
        float sv = sc[qq];
        const float* vr = v + ((size_t)b*Pn+qq)*Hn + t;
        a0 += sv*vr[0]; a1 += sv*vr[256]; a2 += sv*vr[512];
    }
    const float* pt = pairT + (size_t)row*Hn + t;
    float* o = pair2 + (size_t)row*Hn + t;
    o[0]   = tanhf(pt[0])   + a0*invs;
    o[256] = tanhf(pt[256]) + a1*invs;
    o[512] = tanhf(pt[512]) + a2*invs;
}

__global__ __launch_bounds__(256) void k_fillu(unsigned int* p, unsigned int v, int n){
    int i = blockIdx.x*256 + threadIdx.x;
    if (i < n) p[i] = v;
}

// ---------------- launch ----------------
extern "C" void kernel_launch(void* const* d_in, const int* in_sizes, int n_in,
                              void* d_out, int out_size, void* d_ws, size_t ws_size,
                              hipStream_t stream)
{
    const float* seq  = (const float*)d_in[0];
    const float* att  = (const float*)d_in[1];
    const int*   midx = (const int*)d_in[2];
    const float* mmask= (const float*)d_in[3];
    const int*   hts  = (const int*)d_in[4];
    const float* vis  = (const float*)d_in[5];
    const float* Wcq = (const float*)d_in[6];  const float* bcq = (const float*)d_in[7];
    const float* Weq = (const float*)d_in[8];  const float* beq = (const float*)d_in[9];
    const float* Whe = (const float*)d_in[10]; const float* bhe = (const float*)d_in[11];
    const float* Wte = (const float*)d_in[12]; const float* bte = (const float*)d_in[13];
    const float* Wbl = (const float*)d_in[14]; const float* bbl = (const float*)d_in[15];
    const float* Wpp = (const float*)d_in[16]; const float* bpp = (const float*)d_in[17];
    const float* Wgq = (const float*)d_in[18];
    const float* Wgk = (const float*)d_in[19];
    const float* Wgv = (const float*)d_in[20];
    const float* Wp1 = (const float*)d_in[21]; const float* bp1 = (const float*)d_in[22];
    const float* Wp2 = (const float*)d_in[23]; const float* bp2 = (const float*)d_in[24];
    const float* pos = (const float*)d_in[25];
    float* ws = (float*)d_ws;
    float* out = (float*)d_out;
    const float* nul = nullptr;
    float* nulw = nullptr;

    if (ws_size < 89505792ULL) {
        int n = out_size/2;
        k_fillu<<<(n+255)/256, 256, 0, stream>>>((unsigned int*)d_out, 0x476A476Au, n);
        return;
    }

    unsigned short* WCQt = (unsigned short*)(ws + oWCQ);
    unsigned short* WEQt = (unsigned short*)(ws + oWEQ);
    unsigned short* SEQt = (unsigned short*)(ws + oSEQT);
    unsigned short* WHEt = (unsigned short*)(ws + oWHE);
    unsigned short* WTEt = (unsigned short*)(ws + oWTE);
    unsigned short* WBLt = (unsigned short*)(ws + oWBL);
    unsigned short* WPPt = (unsigned short*)(ws + oWPP);
    unsigned short* WGQt = (unsigned short*)(ws + oWGQ);
    unsigned short* WP1t = (unsigned short*)(ws + oWP1);
    unsigned short* WP2t = (unsigned short*)(ws + oWP2);

    // ---- front-end ----
    k_ent_att<<<Bn*NEn*NHn, 256, 0, stream>>>(att, midx, mmask, ws + oEA);
    k_ent_emb<<<Bn*NEn*MMn, 256, 0, stream>>>(seq, midx, mmask, ws + oEE);
    k_htatt<<<Mr, 256, 0, stream>>>(ws + oEA, hts, ws + oHA);

    // Wcq/Weq + per-batch seq transposes (EA dead)
    {
        WT8 tb{}; tb.nd = 6;
        tb.d[0] = { Wcq, WCQt, 768, 128, 128, 0 };
        tb.d[1] = { Weq, WEQt, 768, 128, 128, 24 };
        for (int b = 0; b < 4; b++)
            tb.d[2+b] = { seq + (size_t)b*Cn*Hn, SEQt + (size_t)b*Hn*Cn, Cn, Hn, Hn, 48 + b*96 };
        k_wtr<<<432, 256, 0, stream>>>(tb);
    }
    // rs = ht_att @ seq[b]   (batched MFMA)
    k_gmfma<32,0><<<dim3(6,12,4), 256, 0, stream>>>(ws + oHA, nul, nul, Cn, 0, 0,
        SEQt, nul, ws + oRS, nulw, nulw, Pn, Hn, 0,
        (long)Pn*Cn, (long)Hn*Cn, (long)Pn*Hn);
    // htq = rs @ Wcq + bcq
    k_gmfma<4,0><<<dim3(24,2,1), 256, 0, stream>>>(ws + oRS, nul, nul, Hn, 0, 0,
        WCQt, bcq, ws + oHQ, nulw, nulw, Mr, QSn, 0, 0, 0, 0);
    // ent_key = ent_emb @ Weq + beq
    k_gmfma<4,0><<<dim3(29,2,1), 256, 0, stream>>>(ws + oEE, nul, nul, Hn, 0, 0,
        WEQt, beq, ws + oEK, nulw, nulw, Bn*NEn*MMn, QSn, 0, 0, 0, 0);
    k_select<<<dim3(Mr,2), 256, 0, stream>>>(ws + oHQ, ws + oEK, ws + oEE,
        mmask, hts, ws + oSH, ws + oST);

    // Whe/Wte transposes (EA/EE/EK/HQ dead)
    {
        WT8 tb{}; tb.nd = 2;
        tb.d[0] = { Whe, WHEt, 1536, 768, 768, 0 };
        tb.d[1] = { Wte, WTEt, 1536, 768, 768, 288 };
        k_wtr<<<576, 256, 0, stream>>>(tb);
    }
    // bias-init hs/ts/pb in one pass (contiguous), then atomic k-split GEMMs (raw, tanh at consumers)
    k_binit3<<<(3*Mr*Hn)/256, 256, 0, stream>>>(bhe, bte, bbl, ws + o_HS);
    k_gmfma<1,0><<<dim3(24,12,3), 256, 0, stream>>>(ws + oSH, ws + oRS, nul, Hn, Hn, 0,
        WHEt, nul, ws + o_HS, nulw, nulw, Mr, Hn, 512, 0, 0, 0);
    k_gmfma<1,0><<<dim3(24,12,3), 256, 0, stream>>>(ws + oST, ws + oRS, nul, Hn, Hn, 0,
        WTEt, nul, ws + o_TS, nulw, nulw, Mr, Hn, 512, 0, 0, 0);

    // bilinear: Wbl transpose (all X dead), MFMA v2
    {
        WT8 tb{}; tb.nd = 1;
        tb.d[0] = { Wbl, WBLt, 49152, 768, 768, 0 };
        k_wtr<<<9216, 256, 0, stream>>>(tb);
    }
    k_blmfma<<<dim3(24,6,6), 256, 0, stream>>>(ws + o_HS, ws + o_TS, WBLt, ws + o_PB);

    k_featpp<<<Mr, 256, 0, stream>>>(ws + o_PB, pos, hts, ws + oFP);

    // late weight transposes (WblT dead)
    {
        WT8 tb{}; tb.nd = 6;
        tb.d[0] = { Wpp, WPPt, 1024, 768, 768, 0 };
        tb.d[1] = { Wgq, WGQt, 768, 768, 768, 192 };
        tb.d[2] = { Wgk, (unsigned short*)(ws + oWGK), 768, 768, 768, 336 };
        tb.d[3] = { Wgv, (unsigned short*)(ws + oWGV), 768, 768, 768, 480 };
        tb.d[4] = { Wp1, WP1t, 2304, 768, 768, 624 };
        tb.d[5] = { Wp2, WP2t, 768, 97, 128, 1056 };
        k_wtr<<<1080, 256, 0, stream>>>(tb);
    }
    // pairT-acc = fpp @ Wpp + bpp  (raw; tanh at consumers)
    k_binit<<<(Mr*Hn)/256, 256, 0, stream>>>(bpp, ws + oPT, Hn);
    k_gmfma<1,0><<<dim3(24,12,2), 256, 0, stream>>>(ws + oFP, nul, nul, 1024, 0, 0,
        WPPt, nul, ws + oPT, nulw, nulw, Mr, Hn, 512, 0, 0, 0);
    // fused q|kT|v = tanh(pairT) @ [Wgq|Wgk|Wgv]  (weights contiguous, N=2304)
    k_gmfma<16,1><<<dim3(24,36,1), 256, 0, stream>>>(ws + oPT, nul, nul, Hn, 0, 0,
        WGQt, nul, ws + oQ, ws + oKT, ws + oV, Mr, 3*Hn, 0, 0, 0, 0);
    k_graph<<<Mr, 256, 0, stream>>>(ws + oQ, ws + oKT, ws + oV, vis, ws + oPT, ws + oP2);
    // t1-acc = [tanh(hs)|tanh(ts)|pair2] @ Wp1 + bp1  (raw; tanh at final gemm)
    k_binit<<<(Mr*Hn)/256, 256, 0, stream>>>(bp1, ws + oT1, Hn);
    k_gmfma<1,3><<<dim3(24,12,3), 256, 0, stream>>>(ws + o_HS, ws + o_TS, ws + oP2,
        Hn, Hn, Hn, WP1t, nul, ws + oT1, nulw, nulw, Mr, Hn, 768, 0, 0, 0);
    // logits = tanh(t1) @ Wp2 + bp2
    k_gmfma<4,1><<<dim3(24,2,1), 256, 0, stream>>>(ws + oT1, nul, nul, Hn, 0, 0,
        WP2t, bp2, out, nulw, nulw, Mr, 97, 0, 0, 0, 0);
}